// Round 1
// baseline (1050.498 us; speedup 1.0000x reference)
//
#include <hip/hip_runtime.h>
#include <hip/hip_bf16.h>
#include <math.h>

#define B_DIM 2048
#define D_DIM 2048
#define H_DIM 512
#define Z_DIM 500

// activation codes
#define ACT_NONE 0
#define ACT_RELU 1
#define ACT_SIGMOID 2
#define ACT_LEAKY 3

// ---------------- Tiled fp32 GEMM: C = act(A @ W + bias) ----------------
// A: [M,K] row-major, W: [K,N] row-major, C: [M,N]. M % 64 == 0 assumed.
__global__ __launch_bounds__(256) void gemm_kernel(
    const float* __restrict__ A, const float* __restrict__ W,
    const float* __restrict__ bias, float* __restrict__ C,
    int M, int N, int K, int act)
{
    __shared__ __align__(16) float As[16][68];  // transposed A tile, padded
    __shared__ __align__(16) float Bs[16][64];
    const int tid = threadIdx.x;
    const int tx = tid & 15, ty = tid >> 4;
    const int col0 = blockIdx.x * 64, row0 = blockIdx.y * 64;
    float acc[4][4] = {};

    for (int kt = 0; kt < K; kt += 16) {
        // load A tile: 64 rows x 16 k (transpose into As[k][row])
        {
            int r  = tid >> 2;
            int k4 = (tid & 3) << 2;
            int gk = kt + k4;
            const float* ap = A + (size_t)(row0 + r) * K + gk;
            float4 v;
            if (gk + 3 < K) {
                v = *(const float4*)ap;
            } else {
                v.x = (gk     < K) ? ap[0] : 0.f;
                v.y = (gk + 1 < K) ? ap[1] : 0.f;
                v.z = (gk + 2 < K) ? ap[2] : 0.f;
                v.w = (gk + 3 < K) ? ap[3] : 0.f;
            }
            As[k4    ][r] = v.x;
            As[k4 + 1][r] = v.y;
            As[k4 + 2][r] = v.z;
            As[k4 + 3][r] = v.w;
        }
        // load B tile: 16 k x 64 cols
        {
            int kr = tid >> 4;
            int c4 = (tid & 15) << 2;
            int gk = kt + kr, gc = col0 + c4;
            float4 v = make_float4(0.f, 0.f, 0.f, 0.f);
            if (gk < K) {
                const float* wp = W + (size_t)gk * N + gc;
                if (gc + 3 < N) {
                    v = *(const float4*)wp;
                } else {
                    if (gc     < N) v.x = wp[0];
                    if (gc + 1 < N) v.y = wp[1];
                    if (gc + 2 < N) v.z = wp[2];
                    if (gc + 3 < N) v.w = wp[3];
                }
            }
            *(float4*)&Bs[kr][c4] = v;
        }
        __syncthreads();
        #pragma unroll
        for (int kk = 0; kk < 16; ++kk) {
            float4 a4 = *(const float4*)&As[kk][ty << 2];
            float4 b4 = *(const float4*)&Bs[kk][tx << 2];
            float av[4] = {a4.x, a4.y, a4.z, a4.w};
            float bv[4] = {b4.x, b4.y, b4.z, b4.w};
            #pragma unroll
            for (int i = 0; i < 4; ++i)
                #pragma unroll
                for (int j = 0; j < 4; ++j)
                    acc[i][j] += av[i] * bv[j];
        }
        __syncthreads();
    }

    #pragma unroll
    for (int i = 0; i < 4; ++i) {
        int r = row0 + (ty << 2) + i;
        #pragma unroll
        for (int j = 0; j < 4; ++j) {
            int c = col0 + (tx << 2) + j;
            if (c < N) {
                float v = acc[i][j] + bias[c];
                if (act == ACT_SIGMOID) v = 1.f / (1.f + expf(-v));
                C[(size_t)r * N + c] = v;
            }
        }
    }
}

// ---------------- BatchNorm column stats (partial) ----------------
// grid: (N/64, G). Each block: 64 cols x 4 row-threads, reduces rowsPerBlock rows.
__global__ __launch_bounds__(256) void colstats_partial(
    const float* __restrict__ Y, float* __restrict__ part,
    int Brows, int N, int rowsPerBlock)
{
    const int t = threadIdx.x;
    const int col = blockIdx.x * 64 + (t & 63);
    const int g = blockIdx.y;
    const int r0 = g * rowsPerBlock;
    const int r1 = min(r0 + rowsPerBlock, Brows);
    float s = 0.f, s2 = 0.f;
    for (int r = r0 + (t >> 6); r < r1; r += 4) {
        float v = Y[(size_t)r * N + col];
        s += v;
        s2 += v * v;
    }
    __shared__ float ss[4][64], ss2[4][64];
    ss[t >> 6][t & 63] = s;
    ss2[t >> 6][t & 63] = s2;
    __syncthreads();
    if (t < 64) {
        s  = ss[0][t] + ss[1][t] + ss[2][t] + ss[3][t];
        s2 = ss2[0][t] + ss2[1][t] + ss2[2][t] + ss2[3][t];
        float* p = part + ((size_t)g * N + col) * 2;
        p[0] = s;
        p[1] = s2;
    }
}

// finalize: scale = g * rsqrt(var+eps); shift = beta - mean*scale
__global__ __launch_bounds__(256) void colstats_final(
    const float* __restrict__ part, int G, int N, int Brows,
    const float* __restrict__ gamma, const float* __restrict__ beta,
    float* __restrict__ scale, float* __restrict__ shift)
{
    int c = blockIdx.x * 256 + threadIdx.x;
    if (c >= N) return;
    float s = 0.f, s2 = 0.f;
    for (int g = 0; g < G; ++g) {
        s  += part[((size_t)g * N + c) * 2];
        s2 += part[((size_t)g * N + c) * 2 + 1];
    }
    float invB = 1.f / (float)Brows;
    float mean = s * invB;
    float var  = s2 * invB - mean * mean;
    float rstd = rsqrtf(var + 1e-5f);
    float sc = gamma[c] * rstd;
    scale[c] = sc;
    shift[c] = beta[c] - mean * sc;
}

// ---------------- BN apply + activation (float4 elementwise) ----------------
__global__ __launch_bounds__(256) void bn_apply(
    const float* __restrict__ Y, const float* __restrict__ scale,
    const float* __restrict__ shift, float* __restrict__ out,
    int total, int N, int act)
{
    int i4 = (blockIdx.x * 256 + threadIdx.x) * 4;
    if (i4 >= total) return;
    float4 y = *(const float4*)(Y + i4);
    int c = i4 % N;  // N % 4 == 0 -> c..c+3 in same row
    float4 sc = *(const float4*)(scale + c);
    float4 sh = *(const float4*)(shift + c);
    float4 r;
    r.x = y.x * sc.x + sh.x;
    r.y = y.y * sc.y + sh.y;
    r.z = y.z * sc.z + sh.z;
    r.w = y.w * sc.w + sh.w;
    if (act == ACT_RELU) {
        r.x = fmaxf(r.x, 0.f); r.y = fmaxf(r.y, 0.f);
        r.z = fmaxf(r.z, 0.f); r.w = fmaxf(r.w, 0.f);
    } else if (act == ACT_LEAKY) {
        r.x = (r.x >= 0.f) ? r.x : 0.01f * r.x;
        r.y = (r.y >= 0.f) ? r.y : 0.01f * r.y;
        r.z = (r.z >= 0.f) ? r.z : 0.01f * r.z;
        r.w = (r.w >= 0.f) ? r.w : 0.01f * r.w;
    }
    *(float4*)(out + i4) = r;
}

// ---------------- Fused Gumbel subset-sampling scan ----------------
// One block (256 threads) per row. WL in-place: w_logits -> xm = x * khot.
__global__ __launch_bounds__(256) void gumbel_scan_kernel(
    float* __restrict__ WL, const float* __restrict__ U,
    const float* __restrict__ X)
{
    const int row = blockIdx.x;
    const int t = threadIdx.x;
    float* wrow = WL + (size_t)row * D_DIM;
    const float* urow = U + (size_t)row * D_DIM;
    const float* xrow = X + (size_t)row * D_DIM;

    float w[8], oh[8], acc[8];
    __shared__ float smax[4];
    __shared__ float ssum[4];

    #pragma unroll
    for (int j = 0; j < 8; ++j) {
        int c = t + j * 256;
        float u = urow[c];
        u = (1.0f - 1e-10f) * u + 1e-10f;
        w[j] = wrow[c] + logf(-logf(u));
        oh[j] = 0.f;
        acc[j] = 0.f;
    }

    for (int it = 0; it < 64; ++it) {
        float m = -INFINITY;
        #pragma unroll
        for (int j = 0; j < 8; ++j) {
            float mask = fmaxf(1.0f - oh[j], 1e-10f);
            w[j] += logf(mask);
            m = fmaxf(m, w[j]);
        }
        // block max
        #pragma unroll
        for (int off = 32; off; off >>= 1)
            m = fmaxf(m, __shfl_xor(m, off));
        if ((t & 63) == 0) smax[t >> 6] = m;
        __syncthreads();
        m = fmaxf(fmaxf(smax[0], smax[1]), fmaxf(smax[2], smax[3]));

        float s = 0.f;
        #pragma unroll
        for (int j = 0; j < 8; ++j) {
            float e = expf((w[j] - m) * 10.0f);  // softmax(w/T), T=0.1
            oh[j] = e;
            s += e;
        }
        #pragma unroll
        for (int off = 32; off; off >>= 1)
            s += __shfl_xor(s, off);
        if ((t & 63) == 0) ssum[t >> 6] = s;
        __syncthreads();
        s = (ssum[0] + ssum[1]) + (ssum[2] + ssum[3]);
        float inv = 1.0f / s;
        #pragma unroll
        for (int j = 0; j < 8; ++j) {
            oh[j] *= inv;
            acc[j] += oh[j];
        }
    }

    #pragma unroll
    for (int j = 0; j < 8; ++j) {
        int c = t + j * 256;
        wrow[c] = xrow[c] * acc[j];
    }
}

// ---------------- reparameterization: z = mu + eps * exp(0.5*logvar) ----------------
__global__ __launch_bounds__(256) void z_kernel(
    const float* __restrict__ mu, const float* __restrict__ lv,
    const float* __restrict__ eps, float* __restrict__ z, int n4)
{
    int i = blockIdx.x * 256 + threadIdx.x;
    if (i >= n4) return;
    float4 m = ((const float4*)mu)[i];
    float4 l = ((const float4*)lv)[i];
    float4 e = ((const float4*)eps)[i];
    float4 r;
    r.x = m.x + e.x * expf(0.5f * l.x);
    r.y = m.y + e.y * expf(0.5f * l.y);
    r.z = m.z + e.z * expf(0.5f * l.z);
    r.w = m.w + e.w * expf(0.5f * l.w);
    ((float4*)z)[i] = r;
}

extern "C" void kernel_launch(void* const* d_in, const int* in_sizes, int n_in,
                              void* d_out, int out_size, void* d_ws, size_t ws_size,
                              hipStream_t stream) {
    const float* x        = (const float*)d_in[0];
    const float* u_gumbel = (const float*)d_in[1];
    const float* eps      = (const float*)d_in[2];
    const float* wc_w1    = (const float*)d_in[3];
    const float* wc_b1    = (const float*)d_in[4];
    const float* wc_g     = (const float*)d_in[5];
    const float* wc_beta  = (const float*)d_in[6];
    const float* wc_w2    = (const float*)d_in[7];
    const float* wc_b2    = (const float*)d_in[8];
    const float* enc_w1   = (const float*)d_in[9];
    const float* enc_b1   = (const float*)d_in[10];
    const float* enc_g1   = (const float*)d_in[11];
    const float* enc_beta1= (const float*)d_in[12];
    const float* enc_w2   = (const float*)d_in[13];
    const float* enc_b2   = (const float*)d_in[14];
    const float* enc_g2   = (const float*)d_in[15];
    const float* enc_beta2= (const float*)d_in[16];
    const float* enc_w3   = (const float*)d_in[17];
    const float* enc_b3   = (const float*)d_in[18];
    const float* enc_g3   = (const float*)d_in[19];
    const float* enc_beta3= (const float*)d_in[20];
    const float* fc21_w   = (const float*)d_in[21];
    const float* fc21_b   = (const float*)d_in[22];
    const float* fc22_w   = (const float*)d_in[23];
    const float* fc22_b   = (const float*)d_in[24];
    const float* fc3_w    = (const float*)d_in[25];
    const float* fc3_b    = (const float*)d_in[26];
    const float* fc3_g    = (const float*)d_in[27];
    const float* fc3_beta = (const float*)d_in[28];
    const float* fc4_w    = (const float*)d_in[29];
    const float* fc4_b    = (const float*)d_in[30];

    float* out   = (float*)d_out;
    float* mu_x  = out;                                  // [2048, 2048]
    float* mu    = out + (size_t)B_DIM * D_DIM;          // [2048, 500]
    float* lv    = mu + (size_t)B_DIM * Z_DIM;           // [2048, 500]

    float* wsf   = (float*)d_ws;
    float* bufA  = wsf;                    // 2M floats (8 MB)
    float* bufB  = wsf + (2u << 20);       // 4M floats (16 MB)
    float* part  = wsf + (6u << 20);       // 8*1024*2 = 16384 floats
    float* scale = part + 16384;           // 1024
    float* shift = scale + 1024;           // 1024

    const int G = 8;  // row-groups for column stats

    auto gemm = [&](const float* A, const float* W, const float* b, float* C,
                    int M, int N, int K, int act) {
        dim3 grid((N + 63) / 64, M / 64);
        gemm_kernel<<<grid, 256, 0, stream>>>(A, W, b, C, M, N, K, act);
    };
    auto bn = [&](const float* Y, const float* g_, const float* b_, float* O,
                  int N, int act) {
        dim3 gp(N / 64, G);
        colstats_partial<<<gp, 256, 0, stream>>>(Y, part, B_DIM, N, B_DIM / G);
        colstats_final<<<(N + 255) / 256, 256, 0, stream>>>(part, G, N, B_DIM, g_, b_, scale, shift);
        int total = B_DIM * N;
        bn_apply<<<(total / 4 + 255) / 256, 256, 0, stream>>>(Y, scale, shift, O, total, N, act);
    };

    float* Y1 = bufA;                      // [2048,512]
    float* H  = bufA + (1u << 20);         // [2048,512]
    float* WLb= bufB;                      // [2048,2048] -> becomes XM in-place
    float* Y2 = bufA;                      // [2048,1024]
    float* A2 = bufB;                      // [2048,1024]
    float* Y3 = bufA;                      // [2048,512]
    float* A3 = bufA + (1u << 20);         // [2048,512]
    float* Y4 = bufB + (2u << 20);         // [2048,512]
    float* A4 = bufB + (3u << 20);         // [2048,512]
    float* Zb = bufA;                      // [2048,500]
    float* Y5 = bufA + (1u << 20);         // [2048,512]
    float* A5 = bufB;                      // [2048,512]

    // weight_creator
    gemm(x, wc_w1, wc_b1, Y1, B_DIM, H_DIM, D_DIM, ACT_NONE);
    bn(Y1, wc_g, wc_beta, H, H_DIM, ACT_RELU);
    gemm(H, wc_w2, wc_b2, WLb, B_DIM, D_DIM, H_DIM, ACT_NONE);

    // fused gumbel subset scan: WLb -> xm (in place)
    gumbel_scan_kernel<<<B_DIM, 256, 0, stream>>>(WLb, u_gumbel, x);

    // encoder
    gemm(WLb, enc_w1, enc_b1, Y2, B_DIM, 2 * H_DIM, D_DIM, ACT_NONE);
    bn(Y2, enc_g1, enc_beta1, A2, 2 * H_DIM, ACT_LEAKY);
    gemm(A2, enc_w2, enc_b2, Y3, B_DIM, H_DIM, 2 * H_DIM, ACT_NONE);
    bn(Y3, enc_g2, enc_beta2, A3, H_DIM, ACT_LEAKY);
    gemm(A3, enc_w3, enc_b3, Y4, B_DIM, H_DIM, H_DIM, ACT_NONE);
    bn(Y4, enc_g3, enc_beta3, A4, H_DIM, ACT_LEAKY);

    // heads (write directly to outputs)
    gemm(A4, fc21_w, fc21_b, mu, B_DIM, Z_DIM, H_DIM, ACT_NONE);
    gemm(A4, fc22_w, fc22_b, lv, B_DIM, Z_DIM, H_DIM, ACT_NONE);

    // reparameterize
    int n4 = B_DIM * Z_DIM / 4;
    z_kernel<<<(n4 + 255) / 256, 256, 0, stream>>>(mu, lv, eps, Zb, n4);

    // decoder
    gemm(Zb, fc3_w, fc3_b, Y5, B_DIM, H_DIM, Z_DIM, ACT_NONE);
    bn(Y5, fc3_g, fc3_beta, A5, H_DIM, ACT_LEAKY);
    gemm(A5, fc4_w, fc4_b, mu_x, B_DIM, D_DIM, H_DIM, ACT_SIGMOID);
}

// Round 4
// 704.038 us; speedup vs baseline: 1.4921x; 1.4921x over previous
//
#include <hip/hip_runtime.h>
#include <hip/hip_bf16.h>
#include <math.h>

#define B_DIM 2048
#define D_DIM 2048
#define H_DIM 512
#define Z_DIM 500

#define ACT_NONE 0
#define ACT_RELU 1
#define ACT_SIGMOID 2
#define ACT_LEAKY 3

typedef __attribute__((ext_vector_type(8))) _Float16 f16x8;
typedef __attribute__((ext_vector_type(4))) _Float16 f16x4;
typedef __attribute__((ext_vector_type(4))) float f32x4;

// Split f32 a = h + l + r, h/l f16 (RNE). |r| <~ 2^-23 |a| -> fp32-class when
// using 3-term MFMA (h*h + h*l + l*h; dropped l*l ~ 2^-24).
struct HL { _Float16 h, l; };
__device__ __forceinline__ HL split_f16(float a) {
    HL r;
    r.h = (_Float16)a;
    r.l = (_Float16)(a - (float)r.h);
    return r;
}

// ---------------- MFMA split-f16 GEMM: C = act(A @ W + bias) ----------------
// A: [M,K] f32 row-major, W: [K,N] f32 row-major, C: [M,N] f32.
// M % BM == 0. K, N arbitrary (guarded). 256 threads = 4 waves, 2x2 wave grid.
template<int BM, int BN>
__global__ __launch_bounds__(256, 2) void gemm_mfma(
    const float* __restrict__ A, const float* __restrict__ W,
    const float* __restrict__ bias, float* __restrict__ C,
    int M, int N, int K, int act)
{
    constexpr int LDK = 40;              // padded k-stride (f16); 80B row pitch
    constexpr int WM = BM / 2, WN = BN / 2;
    constexpr int MT = WM / 16, NT = WN / 16;
    __shared__ _Float16 smem[(BM + BN) * 2 * LDK];
    _Float16* Ah = smem;
    _Float16* Al = smem + BM * LDK;
    _Float16* Bh = smem + 2 * BM * LDK;
    _Float16* Bl = smem + 2 * BM * LDK + BN * LDK;

    const int t = threadIdx.x;
    const int lane = t & 63;
    const int wv = t >> 6;
    const int wrow = wv >> 1, wcol = wv & 1;
    const int row0 = blockIdx.y * BM, col0 = blockIdx.x * BN;

    f32x4 acc[MT][NT];
    #pragma unroll
    for (int i = 0; i < MT; ++i)
        #pragma unroll
        for (int j = 0; j < NT; ++j) {
            f32x4 z = {0.f, 0.f, 0.f, 0.f};
            acc[i][j] = z;
        }

    // B staging: thread owns column n, KPT consecutive k
    constexpr int TPC = 256 / BN;
    constexpr int KPT = 32 / TPC;
    const int bn_ = t % BN;
    const int bks = (t / BN) * KPT;
    const int gn = col0 + bn_;

    const int ako = (t & 7) * 4;         // A staging k-offset (4 floats)

    for (int kt = 0; kt < K; kt += 32) {
        __syncthreads();
        // ---- stage A tile (BM x 32) as [m][k] hi/lo f16 ----
        {
            const int gk = kt + ako;
            #pragma unroll
            for (int p = 0; p < BM / 32; ++p) {
                int r = p * 32 + (t >> 3);
                const float* ap = A + (size_t)(row0 + r) * K + gk;
                float4 v = make_float4(0.f, 0.f, 0.f, 0.f);
                if (gk + 3 < K) {
                    v = *(const float4*)ap;
                } else {
                    if (gk     < K) v.x = ap[0];
                    if (gk + 1 < K) v.y = ap[1];
                    if (gk + 2 < K) v.z = ap[2];
                    if (gk + 3 < K) v.w = ap[3];
                }
                HL s0 = split_f16(v.x), s1 = split_f16(v.y);
                HL s2 = split_f16(v.z), s3 = split_f16(v.w);
                f16x4 h4 = {s0.h, s1.h, s2.h, s3.h};
                f16x4 l4 = {s0.l, s1.l, s2.l, s3.l};
                *(f16x4*)&Ah[r * LDK + ako] = h4;
                *(f16x4*)&Al[r * LDK + ako] = l4;
            }
        }
        // ---- stage B tile (32 x BN) transposed into [n][k] hi/lo f16 ----
        {
            float bv[KPT];
            #pragma unroll
            for (int i = 0; i < KPT; ++i) {
                int gk = kt + bks + i;
                bv[i] = (gk < K && gn < N) ? W[(size_t)gk * N + gn] : 0.f;
            }
            #pragma unroll
            for (int i = 0; i < KPT; i += 4) {
                HL s0 = split_f16(bv[i    ]), s1 = split_f16(bv[i + 1]);
                HL s2 = split_f16(bv[i + 2]), s3 = split_f16(bv[i + 3]);
                f16x4 h4 = {s0.h, s1.h, s2.h, s3.h};
                f16x4 l4 = {s0.l, s1.l, s2.l, s3.l};
                *(f16x4*)&Bh[bn_ * LDK + bks + i] = h4;
                *(f16x4*)&Bl[bn_ * LDK + bks + i] = l4;
            }
        }
        __syncthreads();
        // ---- compute: fragments + 3-term MFMA ----
        const int q8 = (lane >> 4) * 8;
        const int fr = lane & 15;
        f16x8 ah[MT], al[MT], bh[NT], bl[NT];
        #pragma unroll
        for (int i = 0; i < MT; ++i) {
            int r = wrow * WM + i * 16 + fr;
            ah[i] = *(const f16x8*)&Ah[r * LDK + q8];
            al[i] = *(const f16x8*)&Al[r * LDK + q8];
        }
        #pragma unroll
        for (int j = 0; j < NT; ++j) {
            int n = wcol * WN + j * 16 + fr;
            bh[j] = *(const f16x8*)&Bh[n * LDK + q8];
            bl[j] = *(const f16x8*)&Bl[n * LDK + q8];
        }
        #pragma unroll
        for (int i = 0; i < MT; ++i)
            #pragma unroll
            for (int j = 0; j < NT; ++j) {
                acc[i][j] = __builtin_amdgcn_mfma_f32_16x16x32_f16(ah[i], bh[j], acc[i][j], 0, 0, 0);
                acc[i][j] = __builtin_amdgcn_mfma_f32_16x16x32_f16(ah[i], bl[j], acc[i][j], 0, 0, 0);
                acc[i][j] = __builtin_amdgcn_mfma_f32_16x16x32_f16(al[i], bh[j], acc[i][j], 0, 0, 0);
            }
    }

    // ---- epilogue: bias + activation; C/D: col=lane&15, row=(lane>>4)*4+q ----
    #pragma unroll
    for (int i = 0; i < MT; ++i) {
        int rbase = row0 + wrow * WM + i * 16 + (lane >> 4) * 4;
        #pragma unroll
        for (int j = 0; j < NT; ++j) {
            int c = col0 + wcol * WN + j * 16 + (lane & 15);
            if (c < N) {
                float b = bias[c];
                #pragma unroll
                for (int q = 0; q < 4; ++q) {
                    float v = acc[i][j][q] + b;
                    if (act == ACT_SIGMOID)
                        v = 1.f / (1.f + __builtin_amdgcn_exp2f(-v * 1.44269504f));
                    C[(size_t)(rbase + q) * N + c] = v;
                }
            }
        }
    }
}

// ---------------- BatchNorm column stats (partial) ----------------
__global__ __launch_bounds__(256) void colstats_partial(
    const float* __restrict__ Y, float* __restrict__ part,
    int Brows, int N, int rowsPerBlock)
{
    const int t = threadIdx.x;
    const int col = blockIdx.x * 64 + (t & 63);
    const int g = blockIdx.y;
    const int r0 = g * rowsPerBlock;
    const int r1 = min(r0 + rowsPerBlock, Brows);
    float s = 0.f, s2 = 0.f;
    for (int r = r0 + (t >> 6); r < r1; r += 4) {
        float v = Y[(size_t)r * N + col];
        s += v;
        s2 += v * v;
    }
    __shared__ float ss[4][64], ss2[4][64];
    ss[t >> 6][t & 63] = s;
    ss2[t >> 6][t & 63] = s2;
    __syncthreads();
    if (t < 64) {
        s  = ss[0][t] + ss[1][t] + ss[2][t] + ss[3][t];
        s2 = ss2[0][t] + ss2[1][t] + ss2[2][t] + ss2[3][t];
        float* p = part + ((size_t)g * N + col) * 2;
        p[0] = s;
        p[1] = s2;
    }
}

__global__ __launch_bounds__(256) void colstats_final(
    const float* __restrict__ part, int G, int N, int Brows,
    const float* __restrict__ gamma, const float* __restrict__ beta,
    float* __restrict__ scale, float* __restrict__ shift)
{
    int c = blockIdx.x * 256 + threadIdx.x;
    if (c >= N) return;
    float s = 0.f, s2 = 0.f;
    for (int g = 0; g < G; ++g) {
        s  += part[((size_t)g * N + c) * 2];
        s2 += part[((size_t)g * N + c) * 2 + 1];
    }
    float invB = 1.f / (float)Brows;
    float mean = s * invB;
    float var  = s2 * invB - mean * mean;
    float rstd = rsqrtf(var + 1e-5f);
    float sc = gamma[c] * rstd;
    scale[c] = sc;
    shift[c] = beta[c] - mean * sc;
}

__global__ __launch_bounds__(256) void bn_apply(
    const float* __restrict__ Y, const float* __restrict__ scale,
    const float* __restrict__ shift, float* __restrict__ out,
    int total, int N, int act)
{
    int i4 = (blockIdx.x * 256 + threadIdx.x) * 4;
    if (i4 >= total) return;
    float4 y = *(const float4*)(Y + i4);
    int c = i4 % N;
    float4 sc = *(const float4*)(scale + c);
    float4 sh = *(const float4*)(shift + c);
    float4 r;
    r.x = y.x * sc.x + sh.x;
    r.y = y.y * sc.y + sh.y;
    r.z = y.z * sc.z + sh.z;
    r.w = y.w * sc.w + sh.w;
    if (act == ACT_RELU) {
        r.x = fmaxf(r.x, 0.f); r.y = fmaxf(r.y, 0.f);
        r.z = fmaxf(r.z, 0.f); r.w = fmaxf(r.w, 0.f);
    } else if (act == ACT_LEAKY) {
        r.x = (r.x >= 0.f) ? r.x : 0.01f * r.x;
        r.y = (r.y >= 0.f) ? r.y : 0.01f * r.y;
        r.z = (r.z >= 0.f) ? r.z : 0.01f * r.z;
        r.w = (r.w >= 0.f) ? r.w : 0.01f * r.w;
    }
    *(float4*)(out + i4) = r;
}

// ---------------- Fused Gumbel subset-sampling scan ----------------
// One WAVE per row; 32 elems/lane in registers; shfl-only reductions.
// Log2 domain: w2 = w * log2(e). exp((w-m)/T) = exp2((w2-m2)*10) for T=0.1.
__global__ __launch_bounds__(64) void gumbel_scan_kernel(
    float* __restrict__ WL, const float* __restrict__ U,
    const float* __restrict__ X)
{
    const int row = blockIdx.x;
    const int l = threadIdx.x;
    float* wrow = WL + (size_t)row * D_DIM;
    const float* urow = U + (size_t)row * D_DIM;
    const float* xrow = X + (size_t)row * D_DIM;

    const float L2E = 1.4426950408889634f;       // log2(e)
    const float LOG2LN2 = -0.5287663729448977f;  // log2(ln 2)
    const float C10 = 10.0f;  // log2-domain softmax sharpening for T=0.1

    float w2[32], oh[32], acc[32];
    #pragma unroll
    for (int j = 0; j < 32; ++j) {
        int c = l + j * 64;
        float u = urow[c];
        u = (1.0f - 1e-10f) * u + 1e-10f;
        float tl = -__builtin_amdgcn_logf(u);            // -log2(u) >= 0
        // w2 = (wl + ln(-ln u)) * log2e = wl*log2e + log2(tl) + log2(ln2)
        w2[j] = fmaf(wrow[c], L2E, __builtin_amdgcn_logf(tl) + LOG2LN2);
        oh[j] = 0.f;
        acc[j] = 0.f;
    }

    for (int it = 0; it < 64; ++it) {
        float m = -INFINITY;
        #pragma unroll
        for (int j = 0; j < 32; ++j) {
            float mask = fmaxf(1.0f - oh[j], 1e-10f);
            w2[j] += __builtin_amdgcn_logf(mask);        // += log2(mask)
            m = fmaxf(m, w2[j]);
        }
        #pragma unroll
        for (int off = 32; off; off >>= 1)
            m = fmaxf(m, __shfl_xor(m, off));
        float mc = m * C10;
        float s = 0.f;
        #pragma unroll
        for (int j = 0; j < 32; ++j) {
            float e = __builtin_amdgcn_exp2f(fmaf(w2[j], C10, -mc));  // exp((w-m)/T)
            oh[j] = e;
            s += e;
        }
        #pragma unroll
        for (int off = 32; off; off >>= 1)
            s += __shfl_xor(s, off);
        float inv = 1.0f / s;
        #pragma unroll
        for (int j = 0; j < 32; ++j) {
            oh[j] *= inv;
            acc[j] += oh[j];
        }
    }

    #pragma unroll
    for (int j = 0; j < 32; ++j) {
        int c = l + j * 64;
        wrow[c] = xrow[c] * acc[j];
    }
}

// ---------------- z = mu + eps * exp(0.5*logvar) ----------------
__global__ __launch_bounds__(256) void z_kernel(
    const float* __restrict__ mu, const float* __restrict__ lv,
    const float* __restrict__ eps, float* __restrict__ z, int n4)
{
    int i = blockIdx.x * 256 + threadIdx.x;
    if (i >= n4) return;
    float4 m = ((const float4*)mu)[i];
    float4 l = ((const float4*)lv)[i];
    float4 e = ((const float4*)eps)[i];
    const float HL2E = 0.7213475204444817f;  // 0.5 * log2(e)
    float4 r;
    r.x = m.x + e.x * __builtin_amdgcn_exp2f(l.x * HL2E);
    r.y = m.y + e.y * __builtin_amdgcn_exp2f(l.y * HL2E);
    r.z = m.z + e.z * __builtin_amdgcn_exp2f(l.z * HL2E);
    r.w = m.w + e.w * __builtin_amdgcn_exp2f(l.w * HL2E);
    ((float4*)z)[i] = r;
}

extern "C" void kernel_launch(void* const* d_in, const int* in_sizes, int n_in,
                              void* d_out, int out_size, void* d_ws, size_t ws_size,
                              hipStream_t stream) {
    const float* x        = (const float*)d_in[0];
    const float* u_gumbel = (const float*)d_in[1];
    const float* eps      = (const float*)d_in[2];
    const float* wc_w1    = (const float*)d_in[3];
    const float* wc_b1    = (const float*)d_in[4];
    const float* wc_g     = (const float*)d_in[5];
    const float* wc_beta  = (const float*)d_in[6];
    const float* wc_w2    = (const float*)d_in[7];
    const float* wc_b2    = (const float*)d_in[8];
    const float* enc_w1   = (const float*)d_in[9];
    const float* enc_b1   = (const float*)d_in[10];
    const float* enc_g1   = (const float*)d_in[11];
    const float* enc_beta1= (const float*)d_in[12];
    const float* enc_w2   = (const float*)d_in[13];
    const float* enc_b2   = (const float*)d_in[14];
    const float* enc_g2   = (const float*)d_in[15];
    const float* enc_beta2= (const float*)d_in[16];
    const float* enc_w3   = (const float*)d_in[17];
    const float* enc_b3   = (const float*)d_in[18];
    const float* enc_g3   = (const float*)d_in[19];
    const float* enc_beta3= (const float*)d_in[20];
    const float* fc21_w   = (const float*)d_in[21];
    const float* fc21_b   = (const float*)d_in[22];
    const float* fc22_w   = (const float*)d_in[23];
    const float* fc22_b   = (const float*)d_in[24];
    const float* fc3_w    = (const float*)d_in[25];
    const float* fc3_b    = (const float*)d_in[26];
    const float* fc3_g    = (const float*)d_in[27];
    const float* fc3_beta = (const float*)d_in[28];
    const float* fc4_w    = (const float*)d_in[29];
    const float* fc4_b    = (const float*)d_in[30];

    float* out   = (float*)d_out;
    float* mu_x  = out;                                  // [2048, 2048]
    float* mu    = out + (size_t)B_DIM * D_DIM;          // [2048, 500]
    float* lv    = mu + (size_t)B_DIM * Z_DIM;           // [2048, 500]

    float* wsf   = (float*)d_ws;
    float* bufA  = wsf;                    // 2M floats
    float* bufB  = wsf + (2u << 20);       // 4M floats
    float* part  = wsf + (6u << 20);
    float* scale = part + 16384;
    float* shift = scale + 1024;

    const int G = 8;

    auto gemm = [&](const float* A, const float* W, const float* b, float* C,
                    int M, int N, int K, int act) {
        if (N >= 2048) {
            dim3 grid((N + 63) / 64, M / 128);
            gemm_mfma<128, 64><<<grid, 256, 0, stream>>>(A, W, b, C, M, N, K, act);
        } else {
            dim3 grid((N + 63) / 64, M / 64);
            gemm_mfma<64, 64><<<grid, 256, 0, stream>>>(A, W, b, C, M, N, K, act);
        }
    };
    auto bn = [&](const float* Y, const float* g_, const float* b_, float* O,
                  int N, int act) {
        dim3 gp(N / 64, G);
        colstats_partial<<<gp, 256, 0, stream>>>(Y, part, B_DIM, N, B_DIM / G);
        colstats_final<<<(N + 255) / 256, 256, 0, stream>>>(part, G, N, B_DIM, g_, b_, scale, shift);
        int total = B_DIM * N;
        bn_apply<<<(total / 4 + 255) / 256, 256, 0, stream>>>(Y, scale, shift, O, total, N, act);
    };

    float* Y1 = bufA;                      // [2048,512]
    float* H  = bufA + (1u << 20);         // [2048,512]
    float* WLb= bufB;                      // [2048,2048] -> becomes XM in-place
    float* Y2 = bufA;                      // [2048,1024]
    float* A2 = bufB;                      // [2048,1024]
    float* Y3 = bufA;                      // [2048,512]
    float* A3 = bufA + (1u << 20);         // [2048,512]
    float* Y4 = bufB + (2u << 20);         // [2048,512]
    float* A4 = bufB + (3u << 20);         // [2048,512]
    float* Zb = bufA;                      // [2048,500]
    float* Y5 = bufA + (1u << 20);         // [2048,512]
    float* A5 = bufB;                      // [2048,512]

    // weight_creator
    gemm(x, wc_w1, wc_b1, Y1, B_DIM, H_DIM, D_DIM, ACT_NONE);
    bn(Y1, wc_g, wc_beta, H, H_DIM, ACT_RELU);
    gemm(H, wc_w2, wc_b2, WLb, B_DIM, D_DIM, H_DIM, ACT_NONE);

    // fused gumbel subset scan: WLb -> xm (in place)
    gumbel_scan_kernel<<<B_DIM, 64, 0, stream>>>(WLb, u_gumbel, x);

    // encoder
    gemm(WLb, enc_w1, enc_b1, Y2, B_DIM, 2 * H_DIM, D_DIM, ACT_NONE);
    bn(Y2, enc_g1, enc_beta1, A2, 2 * H_DIM, ACT_LEAKY);
    gemm(A2, enc_w2, enc_b2, Y3, B_DIM, H_DIM, 2 * H_DIM, ACT_NONE);
    bn(Y3, enc_g2, enc_beta2, A3, H_DIM, ACT_LEAKY);
    gemm(A3, enc_w3, enc_b3, Y4, B_DIM, H_DIM, H_DIM, ACT_NONE);
    bn(Y4, enc_g3, enc_beta3, A4, H_DIM, ACT_LEAKY);

    // heads
    gemm(A4, fc21_w, fc21_b, mu, B_DIM, Z_DIM, H_DIM, ACT_NONE);
    gemm(A4, fc22_w, fc22_b, lv, B_DIM, Z_DIM, H_DIM, ACT_NONE);

    // reparameterize
    int n4 = B_DIM * Z_DIM / 4;
    z_kernel<<<(n4 + 255) / 256, 256, 0, stream>>>(mu, lv, eps, Zb, n4);

    // decoder
    gemm(Zb, fc3_w, fc3_b, Y5, B_DIM, H_DIM, Z_DIM, ACT_NONE);
    bn(Y5, fc3_g, fc3_beta, A5, H_DIM, ACT_LEAKY);
    gemm(A5, fc4_w, fc4_b, mu_x, B_DIM, D_DIM, H_DIM, ACT_SIGMOID);
}

// Round 5
// 494.768 us; speedup vs baseline: 2.1232x; 1.4230x over previous
//
#include <hip/hip_runtime.h>
#include <hip/hip_bf16.h>
#include <math.h>

#define B_DIM 2048
#define D_DIM 2048
#define H_DIM 512
#define Z_DIM 500

#define ACT_NONE 0
#define ACT_RELU 1
#define ACT_SIGMOID 2
#define ACT_LEAKY 3

typedef __attribute__((ext_vector_type(8))) _Float16 f16x8;
typedef __attribute__((ext_vector_type(4))) _Float16 f16x4;
typedef __attribute__((ext_vector_type(4))) float f32x4;

// Split f32 a = h + l + r, h/l f16 (RNE). 3-term MFMA (hh + hl + lh) -> ~fp32.
struct HL { _Float16 h, l; };
__device__ __forceinline__ HL split_f16(float a) {
    HL r;
    r.h = (_Float16)a;
    r.l = (_Float16)(a - (float)r.h);
    return r;
}

// ---------------- MFMA GEMM, double-buffered, optional split-K ----------------
// TERMS=3: split-f16 3-term (fp32-class). TERMS=1: single f16.
// A:[M,K] f32, W:[K,N] f32, C:[M,N] f32. M%64==0. 256 thr = 4 waves (2x2).
// If gridDim.z>1: raw partials to part[s*M*N + ...] (no bias/act).
template<int TERMS>
__global__ __launch_bounds__(256, 2) void gemm_k(
    const float* __restrict__ A, const float* __restrict__ W,
    const float* __restrict__ bias, float* __restrict__ C,
    float* __restrict__ part, int M, int N, int K, int act, int Kc)
{
    constexpr int BM = 64, BN = 64, LDK = 40;   // 80B row pitch (16B-aligned)
    constexpr int PS = BM * LDK;                // plane stride (f16 elems)
    constexpr int NP = (TERMS == 3) ? 4 : 2;    // planes per buffer
    __shared__ _Float16 smem[2 * NP * PS];

    const int t = threadIdx.x;
    const int lane = t & 63;
    const int wv = t >> 6;
    const int wrow = wv >> 1, wcol = wv & 1;    // 2x2 waves, 32x32 each
    const int row0 = blockIdx.y * BM, col0 = blockIdx.x * BN;
    const int s = blockIdx.z;
    const int ks = s * Kc;
    const int ke = min(ks + Kc, K);
    const int nk = (ke - ks + 31) >> 5;

    // A staging: rows r = p*32 + (t>>3), k-offset (t&7)*4, p = 0..1
    const int ar = t >> 3;
    const int ako = (t & 7) << 2;
    // B staging: col bn_ = t&63, k = (t>>6)*8 .. +7
    const int bn_ = t & 63;
    const int bks = (t >> 6) << 3;
    const int gn = col0 + bn_;

    float4 aR[2];
    float bR[8];

    auto gload = [&](int kt) {
        int gk = kt + ako;
        #pragma unroll
        for (int p = 0; p < 2; ++p) {
            const float* ap = A + (size_t)(row0 + p * 32 + ar) * K + gk;
            float4 v = make_float4(0.f, 0.f, 0.f, 0.f);
            if (gk + 3 < ke) {
                v = *(const float4*)ap;
            } else {
                if (gk     < ke) v.x = ap[0];
                if (gk + 1 < ke) v.y = ap[1];
                if (gk + 2 < ke) v.z = ap[2];
                if (gk + 3 < ke) v.w = ap[3];
            }
            aR[p] = v;
        }
        #pragma unroll
        for (int i = 0; i < 8; ++i) {
            int gk2 = kt + bks + i;
            bR[i] = (gk2 < ke && gn < N) ? W[(size_t)gk2 * N + gn] : 0.f;
        }
    };

    auto cstore = [&](int b) {
        _Float16* Ah = smem + b * NP * PS;
        _Float16* Al = Ah + PS;                          // TERMS==3 only
        _Float16* Bh = Ah + ((TERMS == 3) ? 2 : 1) * PS;
        _Float16* Bl = Bh + PS;                          // TERMS==3 only
        #pragma unroll
        for (int p = 0; p < 2; ++p) {
            int r = p * 32 + ar;
            float4 v = aR[p];
            if constexpr (TERMS == 3) {
                HL s0 = split_f16(v.x), s1 = split_f16(v.y);
                HL s2 = split_f16(v.z), s3 = split_f16(v.w);
                f16x4 h4 = {s0.h, s1.h, s2.h, s3.h};
                f16x4 l4 = {s0.l, s1.l, s2.l, s3.l};
                *(f16x4*)&Ah[r * LDK + ako] = h4;
                *(f16x4*)&Al[r * LDK + ako] = l4;
            } else {
                f16x4 h4 = {(_Float16)v.x, (_Float16)v.y, (_Float16)v.z, (_Float16)v.w};
                *(f16x4*)&Ah[r * LDK + ako] = h4;
            }
        }
        if constexpr (TERMS == 3) {
            f16x8 h8, l8;
            #pragma unroll
            for (int i = 0; i < 8; ++i) { HL sp = split_f16(bR[i]); h8[i] = sp.h; l8[i] = sp.l; }
            *(f16x8*)&Bh[bn_ * LDK + bks] = h8;
            *(f16x8*)&Bl[bn_ * LDK + bks] = l8;
        } else {
            f16x8 h8;
            #pragma unroll
            for (int i = 0; i < 8; ++i) h8[i] = (_Float16)bR[i];
            *(f16x8*)&Bh[bn_ * LDK + bks] = h8;
        }
    };

    f32x4 acc[2][2];
    #pragma unroll
    for (int i = 0; i < 2; ++i)
        #pragma unroll
        for (int j = 0; j < 2; ++j) {
            f32x4 z = {0.f, 0.f, 0.f, 0.f};
            acc[i][j] = z;
        }

    const int q8 = (lane >> 4) * 8;
    const int fr = lane & 15;

    gload(ks);
    cstore(0);
    __syncthreads();

    for (int it = 0; it < nk; ++it) {
        int cur = it & 1;
        if (it + 1 < nk) gload(ks + (it + 1) * 32);

        // compute from buffer cur
        {
            const _Float16* Ah = smem + cur * NP * PS;
            const _Float16* Al = Ah + PS;
            const _Float16* Bh = Ah + ((TERMS == 3) ? 2 : 1) * PS;
            const _Float16* Bl = Bh + PS;
            f16x8 ah[2], al[2], bh[2], bl[2];
            #pragma unroll
            for (int i = 0; i < 2; ++i) {
                int r = wrow * 32 + i * 16 + fr;
                ah[i] = *(const f16x8*)&Ah[r * LDK + q8];
                if constexpr (TERMS == 3) al[i] = *(const f16x8*)&Al[r * LDK + q8];
            }
            #pragma unroll
            for (int j = 0; j < 2; ++j) {
                int n = wcol * 32 + j * 16 + fr;
                bh[j] = *(const f16x8*)&Bh[n * LDK + q8];
                if constexpr (TERMS == 3) bl[j] = *(const f16x8*)&Bl[n * LDK + q8];
            }
            #pragma unroll
            for (int i = 0; i < 2; ++i)
                #pragma unroll
                for (int j = 0; j < 2; ++j) {
                    acc[i][j] = __builtin_amdgcn_mfma_f32_16x16x32_f16(ah[i], bh[j], acc[i][j], 0, 0, 0);
                    if constexpr (TERMS == 3) {
                        acc[i][j] = __builtin_amdgcn_mfma_f32_16x16x32_f16(ah[i], bl[j], acc[i][j], 0, 0, 0);
                        acc[i][j] = __builtin_amdgcn_mfma_f32_16x16x32_f16(al[i], bh[j], acc[i][j], 0, 0, 0);
                    }
                }
        }

        if (it + 1 < nk) cstore(cur ^ 1);
        __syncthreads();
    }

    // ---- epilogue; C/D: col=lane&15, row=(lane>>4)*4+q ----
    const bool dopart = (gridDim.z > 1);
    float* dst = dopart ? (part + (size_t)s * M * N) : C;
    #pragma unroll
    for (int i = 0; i < 2; ++i) {
        int rbase = row0 + wrow * 32 + i * 16 + (lane >> 4) * 4;
        #pragma unroll
        for (int j = 0; j < 2; ++j) {
            int c = col0 + wcol * 32 + j * 16 + (lane & 15);
            if (c < N) {
                float b = dopart ? 0.f : bias[c];
                #pragma unroll
                for (int q = 0; q < 4; ++q) {
                    float v = acc[i][j][q] + b;
                    if (!dopart && act == ACT_SIGMOID)
                        v = 1.f / (1.f + __builtin_amdgcn_exp2f(-v * 1.44269504f));
                    dst[(size_t)(rbase + q) * N + c] = v;
                }
            }
        }
    }
}

// ---------------- split-K reduce: C = sum_s part[s] + bias ----------------
__global__ __launch_bounds__(256) void reduce_bias(
    const float* __restrict__ part, int S, int MN, int N,
    const float* __restrict__ bias, float* __restrict__ C)
{
    int i = blockIdx.x * 256 + threadIdx.x;
    if (i >= MN) return;
    float s = bias[i % N];
    for (int k = 0; k < S; ++k) s += part[(size_t)k * MN + i];
    C[i] = s;
}

// ---------------- BatchNorm column stats (partial) ----------------
__global__ __launch_bounds__(256) void colstats_partial(
    const float* __restrict__ Y, float* __restrict__ part,
    int Brows, int N, int rowsPerBlock)
{
    const int t = threadIdx.x;
    const int col = blockIdx.x * 64 + (t & 63);
    const int g = blockIdx.y;
    const int r0 = g * rowsPerBlock;
    const int r1 = min(r0 + rowsPerBlock, Brows);
    float s = 0.f, s2 = 0.f;
    for (int r = r0 + (t >> 6); r < r1; r += 4) {
        float v = Y[(size_t)r * N + col];
        s += v;
        s2 += v * v;
    }
    __shared__ float ss[4][64], ss2[4][64];
    ss[t >> 6][t & 63] = s;
    ss2[t >> 6][t & 63] = s2;
    __syncthreads();
    if (t < 64) {
        s  = ss[0][t] + ss[1][t] + ss[2][t] + ss[3][t];
        s2 = ss2[0][t] + ss2[1][t] + ss2[2][t] + ss2[3][t];
        float* p = part + ((size_t)g * N + col) * 2;
        p[0] = s;
        p[1] = s2;
    }
}

__global__ __launch_bounds__(256) void colstats_final(
    const float* __restrict__ part, int G, int N, int Brows,
    const float* __restrict__ gamma, const float* __restrict__ beta,
    float* __restrict__ scale, float* __restrict__ shift)
{
    int c = blockIdx.x * 256 + threadIdx.x;
    if (c >= N) return;
    float s = 0.f, s2 = 0.f;
    for (int g = 0; g < G; ++g) {
        s  += part[((size_t)g * N + c) * 2];
        s2 += part[((size_t)g * N + c) * 2 + 1];
    }
    float invB = 1.f / (float)Brows;
    float mean = s * invB;
    float var  = s2 * invB - mean * mean;
    float rstd = rsqrtf(var + 1e-5f);
    float sc = gamma[c] * rstd;
    scale[c] = sc;
    shift[c] = beta[c] - mean * sc;
}

__global__ __launch_bounds__(256) void bn_apply(
    const float* __restrict__ Y, const float* __restrict__ scale,
    const float* __restrict__ shift, float* __restrict__ out,
    int total, int N, int act)
{
    int i4 = (blockIdx.x * 256 + threadIdx.x) * 4;
    if (i4 >= total) return;
    float4 y = *(const float4*)(Y + i4);
    int c = i4 % N;
    float4 sc = *(const float4*)(scale + c);
    float4 sh = *(const float4*)(shift + c);
    float4 r;
    r.x = y.x * sc.x + sh.x;
    r.y = y.y * sc.y + sh.y;
    r.z = y.z * sc.z + sh.z;
    r.w = y.w * sc.w + sh.w;
    if (act == ACT_RELU) {
        r.x = fmaxf(r.x, 0.f); r.y = fmaxf(r.y, 0.f);
        r.z = fmaxf(r.z, 0.f); r.w = fmaxf(r.w, 0.f);
    } else if (act == ACT_LEAKY) {
        r.x = (r.x >= 0.f) ? r.x : 0.01f * r.x;
        r.y = (r.y >= 0.f) ? r.y : 0.01f * r.y;
        r.z = (r.z >= 0.f) ? r.z : 0.01f * r.z;
        r.w = (r.w >= 0.f) ? r.w : 0.01f * r.w;
    }
    *(float4*)(out + i4) = r;
}

// ---------------- Fused Gumbel subset-sampling scan ----------------
// One WAVE per row; 32 elems/lane; shfl-only reductions. Log2 domain.
__global__ __launch_bounds__(64) void gumbel_scan_kernel(
    float* __restrict__ WL, const float* __restrict__ U,
    const float* __restrict__ X)
{
    const int row = blockIdx.x;
    const int l = threadIdx.x;
    float* wrow = WL + (size_t)row * D_DIM;
    const float* urow = U + (size_t)row * D_DIM;
    const float* xrow = X + (size_t)row * D_DIM;

    const float L2E = 1.4426950408889634f;       // log2(e)
    const float LOG2LN2 = -0.5287663729448977f;  // log2(ln 2)
    const float C10 = 10.0f;                     // log2-domain, T=0.1

    float w2[32], oh[32], acc[32];
    #pragma unroll
    for (int j = 0; j < 32; ++j) {
        int c = l + j * 64;
        float u = urow[c];
        u = (1.0f - 1e-10f) * u + 1e-10f;
        float tl = -__builtin_amdgcn_logf(u);
        w2[j] = fmaf(wrow[c], L2E, __builtin_amdgcn_logf(tl) + LOG2LN2);
        oh[j] = 0.f;
        acc[j] = 0.f;
    }

    for (int it = 0; it < 64; ++it) {
        float m = -INFINITY;
        #pragma unroll
        for (int j = 0; j < 32; ++j) {
            float mask = fmaxf(1.0f - oh[j], 1e-10f);
            w2[j] += __builtin_amdgcn_logf(mask);
            m = fmaxf(m, w2[j]);
        }
        #pragma unroll
        for (int off = 32; off; off >>= 1)
            m = fmaxf(m, __shfl_xor(m, off));
        float mc = m * C10;
        float s = 0.f;
        #pragma unroll
        for (int j = 0; j < 32; ++j) {
            float e = __builtin_amdgcn_exp2f(fmaf(w2[j], C10, -mc));
            oh[j] = e;
            s += e;
        }
        #pragma unroll
        for (int off = 32; off; off >>= 1)
            s += __shfl_xor(s, off);
        float inv = 1.0f / s;
        #pragma unroll
        for (int j = 0; j < 32; ++j) {
            oh[j] *= inv;
            acc[j] += oh[j];
        }
    }

    #pragma unroll
    for (int j = 0; j < 32; ++j) {
        int c = l + j * 64;
        wrow[c] = xrow[c] * acc[j];
    }
}

// ---------------- z = mu + eps * exp(0.5*logvar) ----------------
__global__ __launch_bounds__(256) void z_kernel(
    const float* __restrict__ mu, const float* __restrict__ lv,
    const float* __restrict__ eps, float* __restrict__ z, int n4)
{
    int i = blockIdx.x * 256 + threadIdx.x;
    if (i >= n4) return;
    float4 m = ((const float4*)mu)[i];
    float4 l = ((const float4*)lv)[i];
    float4 e = ((const float4*)eps)[i];
    const float HL2E = 0.7213475204444817f;  // 0.5 * log2(e)
    float4 r;
    r.x = m.x + e.x * __builtin_amdgcn_exp2f(l.x * HL2E);
    r.y = m.y + e.y * __builtin_amdgcn_exp2f(l.y * HL2E);
    r.z = m.z + e.z * __builtin_amdgcn_exp2f(l.z * HL2E);
    r.w = m.w + e.w * __builtin_amdgcn_exp2f(l.w * HL2E);
    ((float4*)z)[i] = r;
}

extern "C" void kernel_launch(void* const* d_in, const int* in_sizes, int n_in,
                              void* d_out, int out_size, void* d_ws, size_t ws_size,
                              hipStream_t stream) {
    const float* x        = (const float*)d_in[0];
    const float* u_gumbel = (const float*)d_in[1];
    const float* eps      = (const float*)d_in[2];
    const float* wc_w1    = (const float*)d_in[3];
    const float* wc_b1    = (const float*)d_in[4];
    const float* wc_g     = (const float*)d_in[5];
    const float* wc_beta  = (const float*)d_in[6];
    const float* wc_w2    = (const float*)d_in[7];
    const float* wc_b2    = (const float*)d_in[8];
    const float* enc_w1   = (const float*)d_in[9];
    const float* enc_b1   = (const float*)d_in[10];
    const float* enc_g1   = (const float*)d_in[11];
    const float* enc_beta1= (const float*)d_in[12];
    const float* enc_w2   = (const float*)d_in[13];
    const float* enc_b2   = (const float*)d_in[14];
    const float* enc_g2   = (const float*)d_in[15];
    const float* enc_beta2= (const float*)d_in[16];
    const float* enc_w3   = (const float*)d_in[17];
    const float* enc_b3   = (const float*)d_in[18];
    const float* enc_g3   = (const float*)d_in[19];
    const float* enc_beta3= (const float*)d_in[20];
    const float* fc21_w   = (const float*)d_in[21];
    const float* fc21_b   = (const float*)d_in[22];
    const float* fc22_w   = (const float*)d_in[23];
    const float* fc22_b   = (const float*)d_in[24];
    const float* fc3_w    = (const float*)d_in[25];
    const float* fc3_b    = (const float*)d_in[26];
    const float* fc3_g    = (const float*)d_in[27];
    const float* fc3_beta = (const float*)d_in[28];
    const float* fc4_w    = (const float*)d_in[29];
    const float* fc4_b    = (const float*)d_in[30];

    float* out   = (float*)d_out;
    float* mu_x  = out;                                  // [2048, 2048]
    float* mu    = out + (size_t)B_DIM * D_DIM;          // [2048, 500]
    float* lv    = mu + (size_t)B_DIM * Z_DIM;           // [2048, 500]

    const size_t MB = 1048576;  // 1M floats
    float* wsf   = (float*)d_ws;
    // layout (floats): [0,2M) Y-region, [1M,5M) wc_w1 partials (early only),
    // [2M,6M) WL/XM, [4M,6M) small partials (after enc_w1), [6M,7M) H,
    // A2@[2M,4M) (after scan-cons.), A3@[1M,2M), A4@[2M,3M), A5@[3M,4M),
    // colstats @ 7M.
    float* Yr    = wsf;                 // Y1/Y2/Y3/Y4/Zb/Y5 region
    float* Pwc1  = wsf + 1 * MB;        // [4][2048,512]
    float* WL    = wsf + 2 * MB;        // [2048,2048] -> XM in place
    float* Psm   = wsf + 4 * MB;        // [2][2048,<=512] small partials
    float* Hbuf  = wsf + 6 * MB;        // [2048,512]
    float* A2    = wsf + 2 * MB;        // [2048,1024] (after XM consumed)
    float* A3    = wsf + 1 * MB;        // [2048,512]
    float* A4    = wsf + 2 * MB;        // [2048,512]
    float* A5    = wsf + 3 * MB;        // [2048,512]
    float* bnp   = wsf + 7 * MB;        // colstats partials
    float* scale = bnp + 16384;
    float* shift = scale + 1024;

    const int G = 8;

    auto gemm = [&](int TERMS, const float* A, const float* W, const float* b,
                    float* C, float* part, int M, int N, int K, int act, int SK) {
        int Kc = ((K / SK + 31) / 32) * 32;
        dim3 grid((N + 63) / 64, M / 64, SK);
        if (TERMS == 3)
            gemm_k<3><<<grid, 256, 0, stream>>>(A, W, b, C, part, M, N, K, act, Kc);
        else
            gemm_k<1><<<grid, 256, 0, stream>>>(A, W, b, C, part, M, N, K, act, Kc);
    };
    auto reduceK = [&](const float* part, int S, int MN, int N, const float* b, float* C) {
        reduce_bias<<<(MN + 255) / 256, 256, 0, stream>>>(part, S, MN, N, b, C);
    };
    auto bn = [&](const float* Y, const float* g_, const float* b_, float* O,
                  int N, int act) {
        dim3 gp(N / 64, G);
        colstats_partial<<<gp, 256, 0, stream>>>(Y, bnp, B_DIM, N, B_DIM / G);
        colstats_final<<<(N + 255) / 256, 256, 0, stream>>>(bnp, G, N, B_DIM, g_, b_, scale, shift);
        int total = B_DIM * N;
        bn_apply<<<(total / 4 + 255) / 256, 256, 0, stream>>>(Y, scale, shift, O, total, N, act);
    };

    float* Y1 = Yr;                       // [2048,512]
    float* Y2 = Yr;                       // [2048,1024]
    float* Y3 = Yr;                       // [2048,512]
    float* Y4 = Yr;                       // [2048,512]
    float* Zb = Yr;                       // [2048,500]
    float* Y5 = Yr + MB / 4;              // [2048,512]

    // ---- weight_creator ----
    // wc_w1: [2048,512] = x @ wc_w1, K=2048, split-K x4, 3-term
    gemm(3, x, wc_w1, wc_b1, nullptr, Pwc1, B_DIM, H_DIM, D_DIM, ACT_NONE, 4);
    reduceK(Pwc1, 4, B_DIM * H_DIM, H_DIM, wc_b1, Y1);
    bn(Y1, wc_g, wc_beta, Hbuf, H_DIM, ACT_RELU);
    // wc_w2: [2048,2048] = H @ wc_w2, K=512, 3-term, direct
    gemm(3, Hbuf, wc_w2, wc_b2, WL, nullptr, B_DIM, D_DIM, H_DIM, ACT_NONE, 1);

    // ---- gumbel scan (in place WL -> XM) ----
    gumbel_scan_kernel<<<B_DIM, 64, 0, stream>>>(WL, u_gumbel, x);

    // ---- encoder ----
    gemm(1, WL, enc_w1, enc_b1, Y2, nullptr, B_DIM, 2 * H_DIM, D_DIM, ACT_NONE, 1);
    bn(Y2, enc_g1, enc_beta1, A2, 2 * H_DIM, ACT_LEAKY);
    gemm(1, A2, enc_w2, enc_b2, nullptr, Psm, B_DIM, H_DIM, 2 * H_DIM, ACT_NONE, 2);
    reduceK(Psm, 2, B_DIM * H_DIM, H_DIM, enc_b2, Y3);
    bn(Y3, enc_g2, enc_beta2, A3, H_DIM, ACT_LEAKY);
    gemm(1, A3, enc_w3, enc_b3, nullptr, Psm, B_DIM, H_DIM, H_DIM, ACT_NONE, 2);
    reduceK(Psm, 2, B_DIM * H_DIM, H_DIM, enc_b3, Y4);
    bn(Y4, enc_g3, enc_beta3, A4, H_DIM, ACT_LEAKY);

    // ---- heads ----
    gemm(1, A4, fc21_w, fc21_b, nullptr, Psm, B_DIM, Z_DIM, H_DIM, ACT_NONE, 2);
    reduceK(Psm, 2, B_DIM * Z_DIM, Z_DIM, fc21_b, mu);
    gemm(1, A4, fc22_w, fc22_b, nullptr, Psm, B_DIM, Z_DIM, H_DIM, ACT_NONE, 2);
    reduceK(Psm, 2, B_DIM * Z_DIM, Z_DIM, fc22_b, lv);

    // ---- reparameterize ----
    int n4 = B_DIM * Z_DIM / 4;
    z_kernel<<<(n4 + 255) / 256, 256, 0, stream>>>(mu, lv, eps, Zb, n4);

    // ---- decoder ----
    gemm(1, Zb, fc3_w, fc3_b, nullptr, Psm, B_DIM, H_DIM, Z_DIM, ACT_NONE, 2);
    reduceK(Psm, 2, B_DIM * H_DIM, H_DIM, fc3_b, Y5);
    bn(Y5, fc3_g, fc3_beta, A5, H_DIM, ACT_LEAKY);
    gemm(1, A5, fc4_w, fc4_b, mu_x, nullptr, B_DIM, D_DIM, H_DIM, ACT_SIGMOID, 1);
}

// Round 6
// 473.664 us; speedup vs baseline: 2.2178x; 1.0446x over previous
//
#include <hip/hip_runtime.h>
#include <hip/hip_bf16.h>
#include <math.h>

#define B_DIM 2048
#define D_DIM 2048
#define H_DIM 512
#define Z_DIM 500

#define ACT_NONE 0
#define ACT_RELU 1
#define ACT_SIGMOID 2
#define ACT_LEAKY 3

typedef __attribute__((ext_vector_type(8))) _Float16 f16x8;
typedef __attribute__((ext_vector_type(4))) _Float16 f16x4;
typedef __attribute__((ext_vector_type(4))) float f32x4;

// Split f32 a = h + l + r, h/l f16 (RNE). 3-term MFMA (hh + hl + lh) -> ~fp32.
struct HL { _Float16 h, l; };
__device__ __forceinline__ HL split_f16(float a) {
    HL r;
    r.h = (_Float16)a;
    r.l = (_Float16)(a - (float)r.h);
    return r;
}

// ---------------- MFMA GEMM, double-buffered, optional split-K ----------------
// TERMS=3: split-f16 3-term (fp32-class). TERMS=1: single f16.
// A:[M,K] f32, W:[K,N] f32, C:[M,N] f32. M%64==0. 256 thr = 4 waves (2x2).
// If gridDim.z>1: raw partials to part[s*M*N + ...] (no bias/act).
template<int TERMS>
__global__ __launch_bounds__(256, 2) void gemm_k(
    const float* __restrict__ A, const float* __restrict__ W,
    const float* __restrict__ bias, float* __restrict__ C,
    float* __restrict__ part, int M, int N, int K, int act, int Kc)
{
    constexpr int BM = 64, BN = 64, LDK = 40;   // 80B row pitch (16B-aligned)
    constexpr int PS = BM * LDK;                // plane stride (f16 elems)
    constexpr int NP = (TERMS == 3) ? 4 : 2;    // planes per buffer
    __shared__ _Float16 smem[2 * NP * PS];

    const int t = threadIdx.x;
    const int lane = t & 63;
    const int wv = t >> 6;
    const int wrow = wv >> 1, wcol = wv & 1;    // 2x2 waves, 32x32 each
    const int row0 = blockIdx.y * BM, col0 = blockIdx.x * BN;
    const int s = blockIdx.z;
    const int ks = s * Kc;
    const int ke = min(ks + Kc, K);
    const int nk = (ke > ks) ? ((ke - ks + 31) >> 5) : 0;

    // A staging: rows r = p*32 + (t>>3), k-offset (t&7)*4, p = 0..1
    const int ar = t >> 3;
    const int ako = (t & 7) << 2;
    // B staging: col bn_ = t&63, k = (t>>6)*8 .. +7
    const int bn_ = t & 63;
    const int bks = (t >> 6) << 3;
    const int gn = col0 + bn_;

    float4 aR[2];
    float bR[8];

    auto gload = [&](int kt) {
        int gk = kt + ako;
        #pragma unroll
        for (int p = 0; p < 2; ++p) {
            const float* ap = A + (size_t)(row0 + p * 32 + ar) * K + gk;
            float4 v = make_float4(0.f, 0.f, 0.f, 0.f);
            if (gk + 3 < ke) {
                v = *(const float4*)ap;
            } else {
                if (gk     < ke) v.x = ap[0];
                if (gk + 1 < ke) v.y = ap[1];
                if (gk + 2 < ke) v.z = ap[2];
                if (gk + 3 < ke) v.w = ap[3];
            }
            aR[p] = v;
        }
        #pragma unroll
        for (int i = 0; i < 8; ++i) {
            int gk2 = kt + bks + i;
            bR[i] = (gk2 < ke && gn < N) ? W[(size_t)gk2 * N + gn] : 0.f;
        }
    };

    auto cstore = [&](int b) {
        _Float16* Ah = smem + b * NP * PS;
        _Float16* Al = Ah + PS;                          // TERMS==3 only
        _Float16* Bh = Ah + ((TERMS == 3) ? 2 : 1) * PS;
        _Float16* Bl = Bh + PS;                          // TERMS==3 only
        #pragma unroll
        for (int p = 0; p < 2; ++p) {
            int r = p * 32 + ar;
            float4 v = aR[p];
            if constexpr (TERMS == 3) {
                HL s0 = split_f16(v.x), s1 = split_f16(v.y);
                HL s2 = split_f16(v.z), s3 = split_f16(v.w);
                f16x4 h4 = {s0.h, s1.h, s2.h, s3.h};
                f16x4 l4 = {s0.l, s1.l, s2.l, s3.l};
                *(f16x4*)&Ah[r * LDK + ako] = h4;
                *(f16x4*)&Al[r * LDK + ako] = l4;
            } else {
                f16x4 h4 = {(_Float16)v.x, (_Float16)v.y, (_Float16)v.z, (_Float16)v.w};
                *(f16x4*)&Ah[r * LDK + ako] = h4;
            }
        }
        if constexpr (TERMS == 3) {
            f16x8 h8, l8;
            #pragma unroll
            for (int i = 0; i < 8; ++i) { HL sp = split_f16(bR[i]); h8[i] = sp.h; l8[i] = sp.l; }
            *(f16x8*)&Bh[bn_ * LDK + bks] = h8;
            *(f16x8*)&Bl[bn_ * LDK + bks] = l8;
        } else {
            f16x8 h8;
            #pragma unroll
            for (int i = 0; i < 8; ++i) h8[i] = (_Float16)bR[i];
            *(f16x8*)&Bh[bn_ * LDK + bks] = h8;
        }
    };

    f32x4 acc[2][2];
    #pragma unroll
    for (int i = 0; i < 2; ++i)
        #pragma unroll
        for (int j = 0; j < 2; ++j) {
            f32x4 z = {0.f, 0.f, 0.f, 0.f};
            acc[i][j] = z;
        }

    const int q8 = (lane >> 4) * 8;
    const int fr = lane & 15;

    gload(ks);
    cstore(0);
    __syncthreads();

    for (int it = 0; it < nk; ++it) {
        int cur = it & 1;
        if (it + 1 < nk) gload(ks + (it + 1) * 32);

        // compute from buffer cur
        {
            const _Float16* Ah = smem + cur * NP * PS;
            const _Float16* Al = Ah + PS;
            const _Float16* Bh = Ah + ((TERMS == 3) ? 2 : 1) * PS;
            const _Float16* Bl = Bh + PS;
            f16x8 ah[2], al[2], bh[2], bl[2];
            #pragma unroll
            for (int i = 0; i < 2; ++i) {
                int r = wrow * 32 + i * 16 + fr;
                ah[i] = *(const f16x8*)&Ah[r * LDK + q8];
                if constexpr (TERMS == 3) al[i] = *(const f16x8*)&Al[r * LDK + q8];
            }
            #pragma unroll
            for (int j = 0; j < 2; ++j) {
                int n = wcol * 32 + j * 16 + fr;
                bh[j] = *(const f16x8*)&Bh[n * LDK + q8];
                if constexpr (TERMS == 3) bl[j] = *(const f16x8*)&Bl[n * LDK + q8];
            }
            #pragma unroll
            for (int i = 0; i < 2; ++i)
                #pragma unroll
                for (int j = 0; j < 2; ++j) {
                    acc[i][j] = __builtin_amdgcn_mfma_f32_16x16x32_f16(ah[i], bh[j], acc[i][j], 0, 0, 0);
                    if constexpr (TERMS == 3) {
                        acc[i][j] = __builtin_amdgcn_mfma_f32_16x16x32_f16(ah[i], bl[j], acc[i][j], 0, 0, 0);
                        acc[i][j] = __builtin_amdgcn_mfma_f32_16x16x32_f16(al[i], bh[j], acc[i][j], 0, 0, 0);
                    }
                }
        }

        if (it + 1 < nk) cstore(cur ^ 1);
        __syncthreads();
    }

    // ---- epilogue; C/D: col=lane&15, row=(lane>>4)*4+q ----
    const bool dopart = (gridDim.z > 1);
    float* dst = dopart ? (part + (size_t)s * M * N) : C;
    #pragma unroll
    for (int i = 0; i < 2; ++i) {
        int rbase = row0 + wrow * 32 + i * 16 + (lane >> 4) * 4;
        #pragma unroll
        for (int j = 0; j < 2; ++j) {
            int c = col0 + wcol * 32 + j * 16 + (lane & 15);
            if (c < N) {
                float b = dopart ? 0.f : bias[c];
                #pragma unroll
                for (int q = 0; q < 4; ++q) {
                    float v = acc[i][j][q] + b;
                    if (!dopart && act == ACT_SIGMOID)
                        v = 1.f / (1.f + __builtin_amdgcn_exp2f(-v * 1.44269504f));
                    dst[(size_t)(rbase + q) * N + c] = v;
                }
            }
        }
    }
}

// ---------------- split-K reduce: C = sum_s part[s] + bias ----------------
__global__ __launch_bounds__(256) void reduce_bias(
    const float* __restrict__ part, int S, int MN, int N,
    const float* __restrict__ bias, float* __restrict__ C)
{
    int i = blockIdx.x * 256 + threadIdx.x;
    if (i >= MN) return;
    float s = bias[i % N];
    for (int k = 0; k < S; ++k) s += part[(size_t)k * MN + i];
    C[i] = s;
}

// ---------------- BatchNorm column stats (partial) ----------------
__global__ __launch_bounds__(256) void colstats_partial(
    const float* __restrict__ Y, float* __restrict__ part,
    int Brows, int N, int rowsPerBlock)
{
    const int t = threadIdx.x;
    const int col = blockIdx.x * 64 + (t & 63);
    const int g = blockIdx.y;
    const int r0 = g * rowsPerBlock;
    const int r1 = min(r0 + rowsPerBlock, Brows);
    float s = 0.f, s2 = 0.f;
    for (int r = r0 + (t >> 6); r < r1; r += 4) {
        float v = Y[(size_t)r * N + col];
        s += v;
        s2 += v * v;
    }
    __shared__ float ss[4][64], ss2[4][64];
    ss[t >> 6][t & 63] = s;
    ss2[t >> 6][t & 63] = s2;
    __syncthreads();
    if (t < 64) {
        s  = ss[0][t] + ss[1][t] + ss[2][t] + ss[3][t];
        s2 = ss2[0][t] + ss2[1][t] + ss2[2][t] + ss2[3][t];
        float* p = part + ((size_t)g * N + col) * 2;
        p[0] = s;
        p[1] = s2;
    }
}

__global__ __launch_bounds__(256) void colstats_final(
    const float* __restrict__ part, int G, int N, int Brows,
    const float* __restrict__ gamma, const float* __restrict__ beta,
    float* __restrict__ scale, float* __restrict__ shift)
{
    int c = blockIdx.x * 256 + threadIdx.x;
    if (c >= N) return;
    float s = 0.f, s2 = 0.f;
    for (int g = 0; g < G; ++g) {
        s  += part[((size_t)g * N + c) * 2];
        s2 += part[((size_t)g * N + c) * 2 + 1];
    }
    float invB = 1.f / (float)Brows;
    float mean = s * invB;
    float var  = s2 * invB - mean * mean;
    float rstd = rsqrtf(var + 1e-5f);
    float sc = gamma[c] * rstd;
    scale[c] = sc;
    shift[c] = beta[c] - mean * sc;
}

__global__ __launch_bounds__(256) void bn_apply(
    const float* __restrict__ Y, const float* __restrict__ scale,
    const float* __restrict__ shift, float* __restrict__ out,
    int total, int N, int act)
{
    int i4 = (blockIdx.x * 256 + threadIdx.x) * 4;
    if (i4 >= total) return;
    float4 y = *(const float4*)(Y + i4);
    int c = i4 % N;
    float4 sc = *(const float4*)(scale + c);
    float4 sh = *(const float4*)(shift + c);
    float4 r;
    r.x = y.x * sc.x + sh.x;
    r.y = y.y * sc.y + sh.y;
    r.z = y.z * sc.z + sh.z;
    r.w = y.w * sc.w + sh.w;
    if (act == ACT_RELU) {
        r.x = fmaxf(r.x, 0.f); r.y = fmaxf(r.y, 0.f);
        r.z = fmaxf(r.z, 0.f); r.w = fmaxf(r.w, 0.f);
    } else if (act == ACT_LEAKY) {
        r.x = (r.x >= 0.f) ? r.x : 0.01f * r.x;
        r.y = (r.y >= 0.f) ? r.y : 0.01f * r.y;
        r.z = (r.z >= 0.f) ? r.z : 0.01f * r.z;
        r.w = (r.w >= 0.f) ? r.w : 0.01f * r.w;
    }
    *(float4*)(out + i4) = r;
}

// ---------------- Fused Gumbel subset-sampling scan ----------------
// 256 threads (4 waves) per row; 8 elems/lane; shfl + tiny-LDS reductions.
// Log2 domain: w2 = w * log2(e). exp((w-m)/T) = exp2((w2-m2)*10) for T=0.1.
__global__ __launch_bounds__(256) void gumbel_scan_kernel(
    float* __restrict__ WL, const float* __restrict__ U,
    const float* __restrict__ X)
{
    const int row = blockIdx.x;
    const int t = threadIdx.x;
    const int wv = t >> 6;
    const int lane = t & 63;
    float* wrow = WL + (size_t)row * D_DIM;
    const float* urow = U + (size_t)row * D_DIM;
    const float* xrow = X + (size_t)row * D_DIM;

    const float L2E = 1.4426950408889634f;       // log2(e)
    const float LOG2LN2 = -0.5287663729448977f;  // log2(ln 2)
    const float C10 = 10.0f;                     // log2-domain, T=0.1

    __shared__ float smax[4], ssum[4];

    float w2[8], oh[8], acc[8];
    #pragma unroll
    for (int j = 0; j < 8; ++j) {
        int c = t + j * 256;
        float u = urow[c];
        u = (1.0f - 1e-10f) * u + 1e-10f;
        float tl = -__builtin_amdgcn_logf(u);
        w2[j] = fmaf(wrow[c], L2E, __builtin_amdgcn_logf(tl) + LOG2LN2);
        oh[j] = 0.f;
        acc[j] = 0.f;
    }

    for (int it = 0; it < 64; ++it) {
        float m = -INFINITY;
        #pragma unroll
        for (int j = 0; j < 8; ++j) {
            float mask = fmaxf(1.0f - oh[j], 1e-10f);
            w2[j] += __builtin_amdgcn_logf(mask);
            m = fmaxf(m, w2[j]);
        }
        #pragma unroll
        for (int off = 32; off; off >>= 1)
            m = fmaxf(m, __shfl_xor(m, off));
        if (lane == 0) smax[wv] = m;
        __syncthreads();
        m = fmaxf(fmaxf(smax[0], smax[1]), fmaxf(smax[2], smax[3]));
        float mc = m * C10;
        float s = 0.f;
        #pragma unroll
        for (int j = 0; j < 8; ++j) {
            float e = __builtin_amdgcn_exp2f(fmaf(w2[j], C10, -mc));
            oh[j] = e;
            s += e;
        }
        #pragma unroll
        for (int off = 32; off; off >>= 1)
            s += __shfl_xor(s, off);
        if (lane == 0) ssum[wv] = s;
        __syncthreads();
        s = (ssum[0] + ssum[1]) + (ssum[2] + ssum[3]);
        float inv = 1.0f / s;
        #pragma unroll
        for (int j = 0; j < 8; ++j) {
            oh[j] *= inv;
            acc[j] += oh[j];
        }
    }

    #pragma unroll
    for (int j = 0; j < 8; ++j) {
        int c = t + j * 256;
        wrow[c] = xrow[c] * acc[j];
    }
}

// ---------------- z = mu + eps * exp(0.5*logvar) ----------------
__global__ __launch_bounds__(256) void z_kernel(
    const float* __restrict__ mu, const float* __restrict__ lv,
    const float* __restrict__ eps, float* __restrict__ z, int n4)
{
    int i = blockIdx.x * 256 + threadIdx.x;
    if (i >= n4) return;
    float4 m = ((const float4*)mu)[i];
    float4 l = ((const float4*)lv)[i];
    float4 e = ((const float4*)eps)[i];
    const float HL2E = 0.7213475204444817f;  // 0.5 * log2(e)
    float4 r;
    r.x = m.x + e.x * __builtin_amdgcn_exp2f(l.x * HL2E);
    r.y = m.y + e.y * __builtin_amdgcn_exp2f(l.y * HL2E);
    r.z = m.z + e.z * __builtin_amdgcn_exp2f(l.z * HL2E);
    r.w = m.w + e.w * __builtin_amdgcn_exp2f(l.w * HL2E);
    ((float4*)z)[i] = r;
}

extern "C" void kernel_launch(void* const* d_in, const int* in_sizes, int n_in,
                              void* d_out, int out_size, void* d_ws, size_t ws_size,
                              hipStream_t stream) {
    const float* x        = (const float*)d_in[0];
    const float* u_gumbel = (const float*)d_in[1];
    const float* eps      = (const float*)d_in[2];
    const float* wc_w1    = (const float*)d_in[3];
    const float* wc_b1    = (const float*)d_in[4];
    const float* wc_g     = (const float*)d_in[5];
    const float* wc_beta  = (const float*)d_in[6];
    const float* wc_w2    = (const float*)d_in[7];
    const float* wc_b2    = (const float*)d_in[8];
    const float* enc_w1   = (const float*)d_in[9];
    const float* enc_b1   = (const float*)d_in[10];
    const float* enc_g1   = (const float*)d_in[11];
    const float* enc_beta1= (const float*)d_in[12];
    const float* enc_w2   = (const float*)d_in[13];
    const float* enc_b2   = (const float*)d_in[14];
    const float* enc_g2   = (const float*)d_in[15];
    const float* enc_beta2= (const float*)d_in[16];
    const float* enc_w3   = (const float*)d_in[17];
    const float* enc_b3   = (const float*)d_in[18];
    const float* enc_g3   = (const float*)d_in[19];
    const float* enc_beta3= (const float*)d_in[20];
    const float* fc21_w   = (const float*)d_in[21];
    const float* fc21_b   = (const float*)d_in[22];
    const float* fc22_w   = (const float*)d_in[23];
    const float* fc22_b   = (const float*)d_in[24];
    const float* fc3_w    = (const float*)d_in[25];
    const float* fc3_b    = (const float*)d_in[26];
    const float* fc3_g    = (const float*)d_in[27];
    const float* fc3_beta = (const float*)d_in[28];
    const float* fc4_w    = (const float*)d_in[29];
    const float* fc4_b    = (const float*)d_in[30];

    float* out   = (float*)d_out;
    float* mu_x  = out;                                  // [2048, 2048]
    float* mu    = out + (size_t)B_DIM * D_DIM;          // [2048, 500]
    float* lv    = mu + (size_t)B_DIM * Z_DIM;           // [2048, 500]

    const size_t M1 = 1048576;  // 1M floats
    float* wsf   = (float*)d_ws;
    // Arena (floats):
    //   [0, 4M)   : WL/XM [2048,2048]; after XM consumed: Y2/A2 [0,2M),
    //               Y3/A3 [2M,3M), Y4/A4 [3M,4M); then Zb [0,1M), Y5/A5 [1M,2M)
    //   [4M, 8M)  : split-K partials (max 4M floats)
    //   [8M, 9M)  : Y1/H [2048,512]
    //   [9M, ..)  : BN stats
    float* WL    = wsf;
    float* P     = wsf + 4 * M1;
    float* Hbuf  = wsf + 8 * M1;
    float* bnp   = wsf + 9 * M1;
    float* scale = bnp + 16384;
    float* shift = scale + 2048;

    float* Y2 = WL;                 // [2048,1024]
    float* Y3 = WL + 2 * M1;        // [2048,512]
    float* Y4 = WL + 3 * M1;        // [2048,512]
    float* Zb = WL;                 // [2048,500]
    float* Y5 = WL + 1 * M1;        // [2048,512]

    const int G = 8;

    auto gemm = [&](int TERMS, const float* A, const float* W, const float* b,
                    float* C, float* part, int M, int N, int K, int act, int SK) {
        int Kc = ((K / SK + 31) / 32) * 32;
        dim3 grid((N + 63) / 64, M / 64, SK);
        if (TERMS == 3)
            gemm_k<3><<<grid, 256, 0, stream>>>(A, W, b, C, part, M, N, K, act, Kc);
        else
            gemm_k<1><<<grid, 256, 0, stream>>>(A, W, b, C, part, M, N, K, act, Kc);
    };
    auto reduceK = [&](const float* part, int S, int MN, int N, const float* b, float* C) {
        reduce_bias<<<(MN + 255) / 256, 256, 0, stream>>>(part, S, MN, N, b, C);
    };
    auto bn = [&](float* Y, const float* g_, const float* b_, int N, int act) {
        dim3 gp(N / 64, G);
        colstats_partial<<<gp, 256, 0, stream>>>(Y, bnp, B_DIM, N, B_DIM / G);
        colstats_final<<<(N + 255) / 256, 256, 0, stream>>>(bnp, G, N, B_DIM, g_, b_, scale, shift);
        int total = B_DIM * N;
        bn_apply<<<(total / 4 + 255) / 256, 256, 0, stream>>>(Y, scale, shift, Y, total, N, act);
    };

    // ---- weight_creator ----
    gemm(3, x, wc_w1, nullptr, nullptr, P, B_DIM, H_DIM, D_DIM, ACT_NONE, 4);
    reduceK(P, 4, B_DIM * H_DIM, H_DIM, wc_b1, Hbuf);
    bn(Hbuf, wc_g, wc_beta, H_DIM, ACT_RELU);
    gemm(3, Hbuf, wc_w2, wc_b2, WL, nullptr, B_DIM, D_DIM, H_DIM, ACT_NONE, 1);

    // ---- gumbel scan (in place WL -> XM) ----
    gumbel_scan_kernel<<<B_DIM, 256, 0, stream>>>(WL, u_gumbel, x);

    // ---- encoder ----
    gemm(1, WL, enc_w1, nullptr, nullptr, P, B_DIM, 2 * H_DIM, D_DIM, ACT_NONE, 2);
    reduceK(P, 2, B_DIM * 2 * H_DIM, 2 * H_DIM, enc_b1, Y2);
    bn(Y2, enc_g1, enc_beta1, 2 * H_DIM, ACT_LEAKY);
    gemm(1, Y2, enc_w2, nullptr, nullptr, P, B_DIM, H_DIM, 2 * H_DIM, ACT_NONE, 4);
    reduceK(P, 4, B_DIM * H_DIM, H_DIM, enc_b2, Y3);
    bn(Y3, enc_g2, enc_beta2, H_DIM, ACT_LEAKY);
    gemm(1, Y3, enc_w3, nullptr, nullptr, P, B_DIM, H_DIM, H_DIM, ACT_NONE, 4);
    reduceK(P, 4, B_DIM * H_DIM, H_DIM, enc_b3, Y4);
    bn(Y4, enc_g3, enc_beta3, H_DIM, ACT_LEAKY);

    // ---- heads ----
    gemm(1, Y4, fc21_w, nullptr, nullptr, P, B_DIM, Z_DIM, H_DIM, ACT_NONE, 4);
    reduceK(P, 4, B_DIM * Z_DIM, Z_DIM, fc21_b, mu);
    gemm(1, Y4, fc22_w, nullptr, nullptr, P, B_DIM, Z_DIM, H_DIM, ACT_NONE, 4);
    reduceK(P, 4, B_DIM * Z_DIM, Z_DIM, fc22_b, lv);

    // ---- reparameterize ----
    int n4 = B_DIM * Z_DIM / 4;
    z_kernel<<<(n4 + 255) / 256, 256, 0, stream>>>(mu, lv, eps, Zb, n4);

    // ---- decoder ----
    gemm(1, Zb, fc3_w, nullptr, nullptr, P, B_DIM, H_DIM, Z_DIM, ACT_NONE, 4);
    reduceK(P, 4, B_DIM * H_DIM, H_DIM, fc3_b, Y5);
    bn(Y5, fc3_g, fc3_beta, H_DIM, ACT_LEAKY);
    gemm(1, Y5, fc4_w, fc4_b, mu_x, nullptr, B_DIM, D_DIM, H_DIM, ACT_SIGMOID, 1);
}

// Round 7
// 465.189 us; speedup vs baseline: 2.2582x; 1.0182x over previous
//
#include <hip/hip_runtime.h>
#include <hip/hip_bf16.h>
#include <math.h>

#define B_DIM 2048
#define D_DIM 2048
#define H_DIM 512
#define Z_DIM 500

#define ACT_NONE 0
#define ACT_RELU 1
#define ACT_SIGMOID 2
#define ACT_LEAKY 3

typedef __attribute__((ext_vector_type(8))) _Float16 f16x8;
typedef __attribute__((ext_vector_type(4))) _Float16 f16x4;
typedef __attribute__((ext_vector_type(4))) float f32x4;

// ============ MFMA f16 GEMM, 128x64 tile, double-buffered, split-K ==========
// A: [M,K] f16 (h & optional l plane), B: [N,K] f16 (pre-transposed weights).
// TERMS=3: 3-term split-f16 (fp32-class). TERMS=1: plain f16.
// Requires: M%128==0, Kc%32==0, K%32==0, B padded to N%64==0 rows.
// gridDim.z>1 -> raw partials (no bias/act).
template<int BM, int BN, int TERMS>
__global__ __launch_bounds__(256, 2) void gemm_f16(
    const _Float16* __restrict__ Ah_, const _Float16* __restrict__ Al_,
    const _Float16* __restrict__ Bh_, const _Float16* __restrict__ Bl_,
    const float* __restrict__ bias, float* __restrict__ C,
    float* __restrict__ part, int M, int N, int K, int act, int Kc)
{
    constexpr int LDK = 40;                     // 80B pitch, 2-way (free) conflicts
    constexpr int NPL = (TERMS == 3) ? 2 : 1;
    constexpr int PSA = BM * LDK, PSB = BN * LDK;
    constexpr int BUF = NPL * (PSA + PSB);
    constexpr int MT = BM / 32, NT = BN / 32;   // per-wave 16x16 tiles (2x2 waves)
    constexpr int CA = BM / 64, CB = BN / 64;   // 16B chunks per thread
    __shared__ _Float16 smem[2 * BUF];

    const int t = threadIdx.x, lane = t & 63, wv = t >> 6;
    const int wrow = wv >> 1, wcol = wv & 1;
    const int row0 = blockIdx.y * BM, col0 = blockIdx.x * BN;
    const int ks = blockIdx.z * Kc;
    const int nk = Kc >> 5;

    f16x8 rA[CA][NPL], rB[CB][NPL];

    auto gload = [&](int kt) {
        #pragma unroll
        for (int i = 0; i < CA; ++i) {
            int id = t + i * 256;
            int r = id >> 2, ko = (id & 3) * 8;
            size_t off = (size_t)(row0 + r) * K + kt + ko;
            rA[i][0] = *(const f16x8*)(Ah_ + off);
            if constexpr (TERMS == 3) rA[i][1] = *(const f16x8*)(Al_ + off);
        }
        #pragma unroll
        for (int i = 0; i < CB; ++i) {
            int id = t + i * 256;
            int r = id >> 2, ko = (id & 3) * 8;
            size_t off = (size_t)(col0 + r) * K + kt + ko;
            rB[i][0] = *(const f16x8*)(Bh_ + off);
            if constexpr (TERMS == 3) rB[i][1] = *(const f16x8*)(Bl_ + off);
        }
    };
    auto cstore = [&](int b) {
        _Float16* base = smem + b * BUF;
        #pragma unroll
        for (int i = 0; i < CA; ++i) {
            int id = t + i * 256;
            int r = id >> 2, ko = (id & 3) * 8;
            *(f16x8*)&base[r * LDK + ko] = rA[i][0];
            if constexpr (TERMS == 3) *(f16x8*)&base[PSA + r * LDK + ko] = rA[i][1];
        }
        _Float16* bb = base + NPL * PSA;
        #pragma unroll
        for (int i = 0; i < CB; ++i) {
            int id = t + i * 256;
            int r = id >> 2, ko = (id & 3) * 8;
            *(f16x8*)&bb[r * LDK + ko] = rB[i][0];
            if constexpr (TERMS == 3) *(f16x8*)&bb[PSB + r * LDK + ko] = rB[i][1];
        }
    };

    f32x4 acc[MT][NT];
    #pragma unroll
    for (int i = 0; i < MT; ++i)
        #pragma unroll
        for (int j = 0; j < NT; ++j) {
            f32x4 z = {0.f, 0.f, 0.f, 0.f};
            acc[i][j] = z;
        }

    const int q8 = (lane >> 4) * 8, fr = lane & 15;

    gload(ks);
    cstore(0);
    __syncthreads();

    for (int it = 0; it < nk; ++it) {
        int cur = it & 1;
        if (it + 1 < nk) gload(ks + (it + 1) * 32);

        const _Float16* A0 = smem + cur * BUF;
        const _Float16* A1 = A0 + PSA;
        const _Float16* B0 = A0 + NPL * PSA;
        const _Float16* B1 = B0 + PSB;
        f16x8 ah[MT], al[MT], bh[NT], bl[NT];
        #pragma unroll
        for (int i = 0; i < MT; ++i) {
            int r = wrow * (BM / 2) + i * 16 + fr;
            ah[i] = *(const f16x8*)&A0[r * LDK + q8];
            if constexpr (TERMS == 3) al[i] = *(const f16x8*)&A1[r * LDK + q8];
        }
        #pragma unroll
        for (int j = 0; j < NT; ++j) {
            int n = wcol * (BN / 2) + j * 16 + fr;
            bh[j] = *(const f16x8*)&B0[n * LDK + q8];
            if constexpr (TERMS == 3) bl[j] = *(const f16x8*)&B1[n * LDK + q8];
        }
        #pragma unroll
        for (int i = 0; i < MT; ++i)
            #pragma unroll
            for (int j = 0; j < NT; ++j) {
                acc[i][j] = __builtin_amdgcn_mfma_f32_16x16x32_f16(ah[i], bh[j], acc[i][j], 0, 0, 0);
                if constexpr (TERMS == 3) {
                    acc[i][j] = __builtin_amdgcn_mfma_f32_16x16x32_f16(ah[i], bl[j], acc[i][j], 0, 0, 0);
                    acc[i][j] = __builtin_amdgcn_mfma_f32_16x16x32_f16(al[i], bh[j], acc[i][j], 0, 0, 0);
                }
            }

        if (it + 1 < nk) cstore(cur ^ 1);
        __syncthreads();
    }

    // epilogue; C/D: col=lane&15, row=(lane>>4)*4+q
    const bool dopart = (gridDim.z > 1);
    float* dst = dopart ? (part + (size_t)blockIdx.z * M * N) : C;
    #pragma unroll
    for (int i = 0; i < MT; ++i) {
        int rbase = row0 + wrow * (BM / 2) + i * 16 + (lane >> 4) * 4;
        #pragma unroll
        for (int j = 0; j < NT; ++j) {
            int c = col0 + wcol * (BN / 2) + j * 16 + (lane & 15);
            if (c < N) {
                float b = dopart ? 0.f : bias[c];
                #pragma unroll
                for (int q = 0; q < 4; ++q) {
                    float v = acc[i][j][q] + b;
                    if (!dopart && act == ACT_SIGMOID)
                        v = 1.f / (1.f + __builtin_amdgcn_exp2f(-v * 1.44269504f));
                    dst[(size_t)(rbase + q) * N + c] = v;
                }
            }
        }
    }
}

// ============ converters ============
// x [n4 float4s] -> h/l f16 planes
__global__ __launch_bounds__(256) void cvt_split_x(
    const float* __restrict__ x, _Float16* __restrict__ xh,
    _Float16* __restrict__ xl, int n4)
{
    int i = blockIdx.x * 256 + threadIdx.x;
    if (i >= n4) return;
    float4 v = ((const float4*)x)[i];
    f16x4 h, l;
    h[0]=(_Float16)v.x; l[0]=(_Float16)(v.x-(float)h[0]);
    h[1]=(_Float16)v.y; l[1]=(_Float16)(v.y-(float)h[1]);
    h[2]=(_Float16)v.z; l[2]=(_Float16)(v.z-(float)h[2]);
    h[3]=(_Float16)v.w; l[3]=(_Float16)(v.w-(float)h[3]);
    ((f16x4*)xh)[i] = h;
    ((f16x4*)xl)[i] = l;
}

// W [K,N] f32 -> Wt [Np,Kp] f16 (h, optional l), zero-padded
__global__ __launch_bounds__(256) void cvt_w_t(
    const float* __restrict__ in, _Float16* __restrict__ outh,
    _Float16* __restrict__ outl, int K, int N, int Kp)
{
    __shared__ float tile[32][33];
    const int t = threadIdx.x;
    const int tk0 = blockIdx.x * 32, tn0 = blockIdx.y * 32;
    const int lx = t & 31, ly = t >> 5;
    #pragma unroll
    for (int r = 0; r < 4; ++r) {
        int k = tk0 + ly + r * 8, n = tn0 + lx;
        tile[ly + r * 8][lx] = (k < K && n < N) ? in[(size_t)k * N + n] : 0.f;
    }
    __syncthreads();
    #pragma unroll
    for (int r = 0; r < 4; ++r) {
        int n = tn0 + ly + r * 8, k = tk0 + lx;
        float v = tile[lx][ly + r * 8];
        _Float16 h = (_Float16)v;
        outh[(size_t)n * Kp + k] = h;
        if (outl) outl[(size_t)n * Kp + k] = (_Float16)(v - (float)h);
    }
}

// ============ split-K reduce: C = sum_s part[s] + bias ============
__global__ __launch_bounds__(256) void reduce_bias(
    const float* __restrict__ part, int S, int MN, int N,
    const float* __restrict__ bias, float* __restrict__ C, int act)
{
    int i = blockIdx.x * 256 + threadIdx.x;
    if (i >= MN) return;
    float s = bias[i % N];
    for (int k = 0; k < S; ++k) s += part[(size_t)k * MN + i];
    if (act == ACT_SIGMOID) s = 1.f / (1.f + __builtin_amdgcn_exp2f(-s * 1.44269504f));
    C[i] = s;
}

// ============ BatchNorm ============
__global__ __launch_bounds__(256) void colstats_partial(
    const float* __restrict__ Y, float* __restrict__ part,
    int Brows, int N, int rowsPerBlock)
{
    const int t = threadIdx.x;
    const int col = blockIdx.x * 64 + (t & 63);
    const int g = blockIdx.y;
    const int r0 = g * rowsPerBlock;
    const int r1 = min(r0 + rowsPerBlock, Brows);
    float s = 0.f, s2 = 0.f;
    for (int r = r0 + (t >> 6); r < r1; r += 4) {
        float v = Y[(size_t)r * N + col];
        s += v;
        s2 += v * v;
    }
    __shared__ float ss[4][64], ss2[4][64];
    ss[t >> 6][t & 63] = s;
    ss2[t >> 6][t & 63] = s2;
    __syncthreads();
    if (t < 64) {
        s  = ss[0][t] + ss[1][t] + ss[2][t] + ss[3][t];
        s2 = ss2[0][t] + ss2[1][t] + ss2[2][t] + ss2[3][t];
        float* p = part + ((size_t)g * N + col) * 2;
        p[0] = s;
        p[1] = s2;
    }
}

__global__ __launch_bounds__(256) void colstats_final(
    const float* __restrict__ part, int G, int N, int Brows,
    const float* __restrict__ gamma, const float* __restrict__ beta,
    float* __restrict__ scale, float* __restrict__ shift)
{
    int c = blockIdx.x * 256 + threadIdx.x;
    if (c >= N) return;
    float s = 0.f, s2 = 0.f;
    for (int g = 0; g < G; ++g) {
        s  += part[((size_t)g * N + c) * 2];
        s2 += part[((size_t)g * N + c) * 2 + 1];
    }
    float invB = 1.f / (float)Brows;
    float mean = s * invB;
    float var  = s2 * invB - mean * mean;
    float rstd = rsqrtf(var + 1e-5f);
    float sc = gamma[c] * rstd;
    scale[c] = sc;
    shift[c] = beta[c] - mean * sc;
}

// BN apply + act; writes f16 (h, optional residual-l plane). No f32 output.
__global__ __launch_bounds__(256) void bn_apply_f16(
    const float* __restrict__ Y, const float* __restrict__ scale,
    const float* __restrict__ shift, _Float16* __restrict__ oh,
    _Float16* __restrict__ ol, int total, int N, int act)
{
    int idx = blockIdx.x * 256 + threadIdx.x;
    int i4 = idx * 4;
    if (i4 >= total) return;
    float4 y = *(const float4*)(Y + i4);
    int c = i4 % N;
    float4 sc = *(const float4*)(scale + c);
    float4 sh = *(const float4*)(shift + c);
    float r[4];
    r[0] = y.x * sc.x + sh.x;
    r[1] = y.y * sc.y + sh.y;
    r[2] = y.z * sc.z + sh.z;
    r[3] = y.w * sc.w + sh.w;
    #pragma unroll
    for (int q = 0; q < 4; ++q) {
        if (act == ACT_RELU) r[q] = fmaxf(r[q], 0.f);
        else if (act == ACT_LEAKY) r[q] = (r[q] >= 0.f) ? r[q] : 0.01f * r[q];
    }
    f16x4 h;
    #pragma unroll
    for (int q = 0; q < 4; ++q) h[q] = (_Float16)r[q];
    ((f16x4*)oh)[idx] = h;
    if (ol) {
        f16x4 l;
        #pragma unroll
        for (int q = 0; q < 4; ++q) l[q] = (_Float16)(r[q] - (float)h[q]);
        ((f16x4*)ol)[idx] = l;
    }
}

// ============ Gumbel subset scan, linear (W=2^w) space ============
// 256 thr (4 waves) / row, 8 elems/lane. No transcendentals in the loop:
// mask update = multiply; softmax numerators = (W/Wmax)^10 via square chain
// (exact same softmax: ratio-invariant; top ratio = 1 so s >= 1, no NaN path).
__global__ __launch_bounds__(256) void gumbel_scan(
    const float* __restrict__ WLg, const float* __restrict__ U,
    const float* __restrict__ X, _Float16* __restrict__ XM)
{
    const int row = blockIdx.x;
    const int t = threadIdx.x, wv = t >> 6, lane = t & 63;
    const float* wrow = WLg + (size_t)row * D_DIM;
    const float* urow = U + (size_t)row * D_DIM;
    const float* xrow = X + (size_t)row * D_DIM;
    _Float16* xmrow = XM + (size_t)row * D_DIM;

    const float L2E = 1.4426950408889634f;       // log2(e)
    const float LOG2LN2 = -0.5287663729448977f;  // log2(ln 2)

    __shared__ float sW[2][4], sS[2][4];

    float W[8], e[8], acc[8];
    #pragma unroll
    for (int j = 0; j < 8; ++j) {
        int c = t + j * 256;
        float u = fmaf(urow[c], 1.0f - 1e-10f, 1e-10f);
        float tl = -__builtin_amdgcn_logf(u);            // -log2(u)
        float w2 = fmaf(wrow[c], L2E, __builtin_amdgcn_logf(tl) + LOG2LN2);
        W[j] = __builtin_amdgcn_exp2f(w2);               // W = 2^w2
        e[j] = 0.f;
        acc[j] = 0.f;
    }
    float inv = 0.f;

    for (int it = 0; it < 64; ++it) {
        const int p = it & 1;
        float lm = 0.f;
        #pragma unroll
        for (int j = 0; j < 8; ++j) {
            acc[j] = fmaf(e[j], inv, acc[j]);                    // acc += oh_prev
            float msk = fmaxf(fmaf(-e[j], inv, 1.0f), 1e-10f);   // 1 - oh_prev
            W[j] *= msk;
            lm = fmaxf(lm, W[j]);
        }
        #pragma unroll
        for (int off = 32; off; off >>= 1)
            lm = fmaxf(lm, __shfl_xor(lm, off));
        if (lane == 0) sW[p][wv] = lm;
        __syncthreads();
        float Wm = fmaxf(fmaxf(sW[p][0], sW[p][1]), fmaxf(sW[p][2], sW[p][3]));
        float rm = 1.0f / Wm;
        float s = 0.f;
        #pragma unroll
        for (int j = 0; j < 8; ++j) {
            float r1 = W[j] * rm;          // <= 1
            float r2 = r1 * r1;
            float r4 = r2 * r2;
            float r5 = r4 * r1;
            float ee = r5 * r5;            // r^10 = softmax numerator, T=0.1
            e[j] = ee;
            s += ee;
        }
        #pragma unroll
        for (int off = 32; off; off >>= 1)
            s += __shfl_xor(s, off);
        if (lane == 0) sS[p][wv] = s;
        __syncthreads();
        s = (sS[p][0] + sS[p][1]) + (sS[p][2] + sS[p][3]);
        inv = 1.0f / s;
    }

    #pragma unroll
    for (int j = 0; j < 8; ++j) {
        int c = t + j * 256;
        float a = fmaf(e[j], inv, acc[j]);           // last iteration's onehot
        xmrow[c] = (_Float16)(xrow[c] * a);
    }
}

// ============ z = mu + eps * exp(0.5*logvar) -> f16, padded to 512 cols ======
__global__ __launch_bounds__(256) void z_kernel16(
    const float* __restrict__ mu, const float* __restrict__ lv,
    const float* __restrict__ eps, _Float16* __restrict__ zb, int n4)
{
    int i = blockIdx.x * 256 + threadIdx.x;
    if (i >= n4) return;
    int f = i * 4;
    int row = f / Z_DIM, col = f - row * Z_DIM;      // Z_DIM%4==0
    float4 m = *(const float4*)(mu + f);
    float4 l = *(const float4*)(lv + f);
    float4 e = *(const float4*)(eps + f);
    const float HL2E = 0.7213475204444817f;          // 0.5*log2(e)
    f16x4 r;
    r[0] = (_Float16)(m.x + e.x * __builtin_amdgcn_exp2f(l.x * HL2E));
    r[1] = (_Float16)(m.y + e.y * __builtin_amdgcn_exp2f(l.y * HL2E));
    r[2] = (_Float16)(m.z + e.z * __builtin_amdgcn_exp2f(l.z * HL2E));
    r[3] = (_Float16)(m.w + e.w * __builtin_amdgcn_exp2f(l.w * HL2E));
    *(f16x4*)(zb + (size_t)row * 512 + col) = r;
}

extern "C" void kernel_launch(void* const* d_in, const int* in_sizes, int n_in,
                              void* d_out, int out_size, void* d_ws, size_t ws_size,
                              hipStream_t stream) {
    const float* x        = (const float*)d_in[0];
    const float* u_gumbel = (const float*)d_in[1];
    const float* eps      = (const float*)d_in[2];
    const float* wc_w1    = (const float*)d_in[3];
    const float* wc_b1    = (const float*)d_in[4];
    const float* wc_g     = (const float*)d_in[5];
    const float* wc_beta  = (const float*)d_in[6];
    const float* wc_w2    = (const float*)d_in[7];
    const float* wc_b2    = (const float*)d_in[8];
    const float* enc_w1   = (const float*)d_in[9];
    const float* enc_b1   = (const float*)d_in[10];
    const float* enc_g1   = (const float*)d_in[11];
    const float* enc_beta1= (const float*)d_in[12];
    const float* enc_w2   = (const float*)d_in[13];
    const float* enc_b2   = (const float*)d_in[14];
    const float* enc_g2   = (const float*)d_in[15];
    const float* enc_beta2= (const float*)d_in[16];
    const float* enc_w3   = (const float*)d_in[17];
    const float* enc_b3   = (const float*)d_in[18];
    const float* enc_g3   = (const float*)d_in[19];
    const float* enc_beta3= (const float*)d_in[20];
    const float* fc21_w   = (const float*)d_in[21];
    const float* fc21_b   = (const float*)d_in[22];
    const float* fc22_w   = (const float*)d_in[23];
    const float* fc22_b   = (const float*)d_in[24];
    const float* fc3_w    = (const float*)d_in[25];
    const float* fc3_b    = (const float*)d_in[26];
    const float* fc3_g    = (const float*)d_in[27];
    const float* fc3_beta = (const float*)d_in[28];
    const float* fc4_w    = (const float*)d_in[29];
    const float* fc4_b    = (const float*)d_in[30];

    float* out   = (float*)d_out;
    float* mu_x  = out;
    float* mu    = out + (size_t)B_DIM * D_DIM;
    float* lv    = mu + (size_t)B_DIM * Z_DIM;

    const size_t F1M = 1u << 20;                    // 1M floats = 4MiB
    float* wsf = (float*)d_ws;
    // float-offset arena (time-shared):
    float*     P_WL  = wsf;                          // [0,4M): partials / WL
    _Float16*  xh    = (_Float16*)(wsf + 4 * F1M);   // [4M,6M)
    _Float16*  xl    = (_Float16*)(wsf + 6 * F1M);   // [6M,8M)
    _Float16*  xm16  = (_Float16*)(wsf + 4 * F1M);   // reuse after xh dead
    float*     Yb    = wsf + 6 * F1M;                // [6M,8M): Y2..Y5 (xl dead)
    _Float16*  a2    = (_Float16*)(wsf + 8 * F1M);
    _Float16*  a3    = (_Float16*)(wsf + 9 * F1M);
    _Float16*  a4    = (_Float16*)(wsf + 9 * F1M + F1M / 2);
    _Float16*  zb16  = (_Float16*)(wsf + 10 * F1M);
    _Float16*  a5    = (_Float16*)(wsf + 10 * F1M + F1M / 2);
    float*     Hbuf  = wsf + 11 * F1M;
    _Float16*  Hh    = (_Float16*)(wsf + 12 * F1M);
    _Float16*  Hl    = (_Float16*)(wsf + 12 * F1M + F1M / 2);
    _Float16*  w1th  = (_Float16*)(wsf + 13 * F1M);
    _Float16*  w1tl  = (_Float16*)(wsf + 13 * F1M + F1M / 2);
    _Float16*  w2th  = (_Float16*)(wsf + 14 * F1M);
    _Float16*  w2tl  = (_Float16*)(wsf + 14 * F1M + F1M / 2);
    _Float16*  e1t   = (_Float16*)(wsf + 15 * F1M);
    _Float16*  e2t   = (_Float16*)(wsf + 16 * F1M);
    _Float16*  e3t   = (_Float16*)(wsf + 16 * F1M + F1M / 4);
    _Float16*  f21t  = (_Float16*)(wsf + 16 * F1M + 3 * (F1M / 8));
    _Float16*  f22t  = (_Float16*)(wsf + 16 * F1M + 4 * (F1M / 8));
    _Float16*  f3t   = (_Float16*)(wsf + 16 * F1M + 5 * (F1M / 8));
    _Float16*  f4t   = (_Float16*)(wsf + 16 * F1M + 6 * (F1M / 8));
    float*     bnp   = wsf + 17 * F1M + F1M / 4;
    float*     scale = bnp + 16384;
    float*     shift = scale + 2048;

    const int G = 8;

    auto gemm3 = [&](const _Float16* Ah, const _Float16* Al,
                     const _Float16* Bh, const _Float16* Bl,
                     const float* b, float* C, float* part,
                     int N, int K, int SK) {
        dim3 grid((N + 63) / 64, B_DIM / 128, SK);
        gemm_f16<128, 64, 3><<<grid, 256, 0, stream>>>(Ah, Al, Bh, Bl, b, C, part,
                                                       B_DIM, N, K, ACT_NONE, K / SK);
    };
    auto gemm1 = [&](const _Float16* Ah, const _Float16* Bh,
                     const float* b, float* C, float* part,
                     int N, int K, int act, int SK) {
        dim3 grid((N + 63) / 64, B_DIM / 128, SK);
        gemm_f16<128, 64, 1><<<grid, 256, 0, stream>>>(Ah, nullptr, Bh, nullptr, b, C,
                                                       part, B_DIM, N, K, act, K / SK);
    };
    auto reduceK = [&](const float* part, int S, int N, const float* b, float* C) {
        int MN = B_DIM * N;
        reduce_bias<<<(MN + 255) / 256, 256, 0, stream>>>(part, S, MN, N, b, C, ACT_NONE);
    };
    auto bn = [&](const float* Y, const float* g_, const float* b_,
                  _Float16* oh, _Float16* ol, int N, int act) {
        dim3 gp(N / 64, G);
        colstats_partial<<<gp, 256, 0, stream>>>(Y, bnp, B_DIM, N, B_DIM / G);
        colstats_final<<<(N + 255) / 256, 256, 0, stream>>>(bnp, G, N, B_DIM, g_, b_, scale, shift);
        int total = B_DIM * N;
        bn_apply_f16<<<(total / 4 + 255) / 256, 256, 0, stream>>>(Y, scale, shift, oh, ol, total, N, act);
    };
    auto cvtw = [&](const float* in, _Float16* oh, _Float16* ol, int K, int N, int Kp, int Np) {
        dim3 grid(Kp / 32, Np / 32);
        cvt_w_t<<<grid, 256, 0, stream>>>(in, oh, ol, K, N, Kp);
    };

    // ---- converts ----
    cvt_split_x<<<4096, 256, 0, stream>>>(x, xh, xl, B_DIM * D_DIM / 4);
    cvtw(wc_w1, w1th, w1tl, 2048, 512, 2048, 512);
    cvtw(wc_w2, w2th, w2tl, 512, 2048, 512, 2048);
    cvtw(enc_w1, e1t, nullptr, 2048, 1024, 2048, 1024);
    cvtw(enc_w2, e2t, nullptr, 1024, 512, 1024, 512);
    cvtw(enc_w3, e3t, nullptr, 512, 512, 512, 512);
    cvtw(fc21_w, f21t, nullptr, 512, 500, 512, 512);
    cvtw(fc22_w, f22t, nullptr, 512, 500, 512, 512);
    cvtw(fc3_w, f3t, nullptr, 500, 512, 512, 512);
    cvtw(fc4_w, f4t, nullptr, 512, 2048, 512, 2048);

    // ---- weight_creator ----
    gemm3(xh, xl, w1th, w1tl, nullptr, nullptr, P_WL, 512, 2048, 4);
    reduceK(P_WL, 4, 512, wc_b1, Hbuf);
    bn(Hbuf, wc_g, wc_beta, Hh, Hl, 512, ACT_RELU);
    gemm3(Hh, Hl, w2th, w2tl, wc_b2, P_WL, nullptr, 2048, 512, 1);  // -> WL

    // ---- gumbel scan: WL -> xm16 (f16) ----
    gumbel_scan<<<B_DIM, 256, 0, stream>>>(P_WL, u_gumbel, x, xm16);

    // ---- encoder ----
    gemm1(xm16, e1t, nullptr, nullptr, P_WL, 1024, 2048, ACT_NONE, 2);
    reduceK(P_WL, 2, 1024, enc_b1, Yb);
    bn(Yb, enc_g1, enc_beta1, a2, nullptr, 1024, ACT_LEAKY);
    gemm1(a2, e2t, nullptr, nullptr, P_WL, 512, 1024, ACT_NONE, 4);
    reduceK(P_WL, 4, 512, enc_b2, Yb);
    bn(Yb, enc_g2, enc_beta2, a3, nullptr, 512, ACT_LEAKY);
    gemm1(a3, e3t, nullptr, nullptr, P_WL, 512, 512, ACT_NONE, 4);
    reduceK(P_WL, 4, 512, enc_b3, Yb);
    bn(Yb, enc_g3, enc_beta3, a4, nullptr, 512, ACT_LEAKY);

    // ---- heads ----
    gemm1(a4, f21t, nullptr, nullptr, P_WL, 500, 512, ACT_NONE, 4);
    reduceK(P_WL, 4, 500, fc21_b, mu);
    gemm1(a4, f22t, nullptr, nullptr, P_WL, 500, 512, ACT_NONE, 4);
    reduceK(P_WL, 4, 500, fc22_b, lv);

    // ---- reparameterize (zb16 zero-padded to 512 cols) ----
    hipMemsetAsync(zb16, 0, (size_t)B_DIM * 512 * sizeof(_Float16), stream);
    int n4 = B_DIM * Z_DIM / 4;
    z_kernel16<<<(n4 + 255) / 256, 256, 0, stream>>>(mu, lv, eps, zb16, n4);

    // ---- decoder ----
    gemm1(zb16, f3t, nullptr, nullptr, P_WL, 512, 512, ACT_NONE, 4);
    reduceK(P_WL, 4, 512, fc3_b, Yb);
    bn(Yb, fc3_g, fc3_beta, a5, nullptr, 512, ACT_LEAKY);
    gemm1(a5, f4t, fc4_b, mu_x, nullptr, 2048, 512, ACT_SIGMOID, 1);
}

// Round 8
// 455.444 us; speedup vs baseline: 2.3065x; 1.0214x over previous
//
#include <hip/hip_runtime.h>
#include <hip/hip_bf16.h>
#include <math.h>

#define B_DIM 2048
#define D_DIM 2048
#define H_DIM 512
#define Z_DIM 500

#define ACT_NONE 0
#define ACT_RELU 1
#define ACT_SIGMOID 2
#define ACT_LEAKY 3

typedef __attribute__((ext_vector_type(8))) _Float16 f16x8;
typedef __attribute__((ext_vector_type(4))) _Float16 f16x4;
typedef __attribute__((ext_vector_type(4))) float f32x4;
typedef __attribute__((ext_vector_type(2))) float f32x2;

// ============ MFMA f16 GEMM, 128x64 tile, double-buffered, split-K ==========
// A: [M,K] f16 (h & optional l plane), B: [N,K] f16 (pre-transposed weights).
// TERMS=3: 3-term split-f16 (fp32-class). TERMS=1: plain f16.
template<int BM, int BN, int TERMS>
__global__ __launch_bounds__(256, 2) void gemm_f16(
    const _Float16* __restrict__ Ah_, const _Float16* __restrict__ Al_,
    const _Float16* __restrict__ Bh_, const _Float16* __restrict__ Bl_,
    const float* __restrict__ bias, float* __restrict__ C,
    float* __restrict__ part, int M, int N, int K, int act, int Kc)
{
    constexpr int LDK = 40;
    constexpr int NPL = (TERMS == 3) ? 2 : 1;
    constexpr int PSA = BM * LDK, PSB = BN * LDK;
    constexpr int BUF = NPL * (PSA + PSB);
    constexpr int MT = BM / 32, NT = BN / 32;
    constexpr int CA = BM / 64, CB = BN / 64;
    __shared__ _Float16 smem[2 * BUF];

    const int t = threadIdx.x, lane = t & 63, wv = t >> 6;
    const int wrow = wv >> 1, wcol = wv & 1;
    const int row0 = blockIdx.y * BM, col0 = blockIdx.x * BN;
    const int ks = blockIdx.z * Kc;
    const int nk = Kc >> 5;

    f16x8 rA[CA][NPL], rB[CB][NPL];

    auto gload = [&](int kt) {
        #pragma unroll
        for (int i = 0; i < CA; ++i) {
            int id = t + i * 256;
            int r = id >> 2, ko = (id & 3) * 8;
            size_t off = (size_t)(row0 + r) * K + kt + ko;
            rA[i][0] = *(const f16x8*)(Ah_ + off);
            if constexpr (TERMS == 3) rA[i][1] = *(const f16x8*)(Al_ + off);
        }
        #pragma unroll
        for (int i = 0; i < CB; ++i) {
            int id = t + i * 256;
            int r = id >> 2, ko = (id & 3) * 8;
            size_t off = (size_t)(col0 + r) * K + kt + ko;
            rB[i][0] = *(const f16x8*)(Bh_ + off);
            if constexpr (TERMS == 3) rB[i][1] = *(const f16x8*)(Bl_ + off);
        }
    };
    auto cstore = [&](int b) {
        _Float16* base = smem + b * BUF;
        #pragma unroll
        for (int i = 0; i < CA; ++i) {
            int id = t + i * 256;
            int r = id >> 2, ko = (id & 3) * 8;
            *(f16x8*)&base[r * LDK + ko] = rA[i][0];
            if constexpr (TERMS == 3) *(f16x8*)&base[PSA + r * LDK + ko] = rA[i][1];
        }
        _Float16* bb = base + NPL * PSA;
        #pragma unroll
        for (int i = 0; i < CB; ++i) {
            int id = t + i * 256;
            int r = id >> 2, ko = (id & 3) * 8;
            *(f16x8*)&bb[r * LDK + ko] = rB[i][0];
            if constexpr (TERMS == 3) *(f16x8*)&bb[PSB + r * LDK + ko] = rB[i][1];
        }
    };

    f32x4 acc[MT][NT];
    #pragma unroll
    for (int i = 0; i < MT; ++i)
        #pragma unroll
        for (int j = 0; j < NT; ++j) {
            f32x4 z = {0.f, 0.f, 0.f, 0.f};
            acc[i][j] = z;
        }

    const int q8 = (lane >> 4) * 8, fr = lane & 15;

    gload(ks);
    cstore(0);
    __syncthreads();

    for (int it = 0; it < nk; ++it) {
        int cur = it & 1;
        if (it + 1 < nk) gload(ks + (it + 1) * 32);

        const _Float16* A0 = smem + cur * BUF;
        const _Float16* A1 = A0 + PSA;
        const _Float16* B0 = A0 + NPL * PSA;
        const _Float16* B1 = B0 + PSB;
        f16x8 ah[MT], al[MT], bh[NT], bl[NT];
        #pragma unroll
        for (int i = 0; i < MT; ++i) {
            int r = wrow * (BM / 2) + i * 16 + fr;
            ah[i] = *(const f16x8*)&A0[r * LDK + q8];
            if constexpr (TERMS == 3) al[i] = *(const f16x8*)&A1[r * LDK + q8];
        }
        #pragma unroll
        for (int j = 0; j < NT; ++j) {
            int n = wcol * (BN / 2) + j * 16 + fr;
            bh[j] = *(const f16x8*)&B0[n * LDK + q8];
            if constexpr (TERMS == 3) bl[j] = *(const f16x8*)&B1[n * LDK + q8];
        }
        #pragma unroll
        for (int i = 0; i < MT; ++i)
            #pragma unroll
            for (int j = 0; j < NT; ++j) {
                acc[i][j] = __builtin_amdgcn_mfma_f32_16x16x32_f16(ah[i], bh[j], acc[i][j], 0, 0, 0);
                if constexpr (TERMS == 3) {
                    acc[i][j] = __builtin_amdgcn_mfma_f32_16x16x32_f16(ah[i], bl[j], acc[i][j], 0, 0, 0);
                    acc[i][j] = __builtin_amdgcn_mfma_f32_16x16x32_f16(al[i], bh[j], acc[i][j], 0, 0, 0);
                }
            }

        if (it + 1 < nk) cstore(cur ^ 1);
        __syncthreads();
    }

    const bool dopart = (gridDim.z > 1);
    float* dst = dopart ? (part + (size_t)blockIdx.z * M * N) : C;
    #pragma unroll
    for (int i = 0; i < MT; ++i) {
        int rbase = row0 + wrow * (BM / 2) + i * 16 + (lane >> 4) * 4;
        #pragma unroll
        for (int j = 0; j < NT; ++j) {
            int c = col0 + wcol * (BN / 2) + j * 16 + (lane & 15);
            if (c < N) {
                float b = dopart ? 0.f : bias[c];
                #pragma unroll
                for (int q = 0; q < 4; ++q) {
                    float v = acc[i][j][q] + b;
                    if (!dopart && act == ACT_SIGMOID)
                        v = 1.f / (1.f + __builtin_amdgcn_exp2f(-v * 1.44269504f));
                    dst[(size_t)(rbase + q) * N + c] = v;
                }
            }
        }
    }
}

// ============ converters ============
__global__ __launch_bounds__(256) void cvt_split_x(
    const float* __restrict__ x, _Float16* __restrict__ xh,
    _Float16* __restrict__ xl, int n4)
{
    int i = blockIdx.x * 256 + threadIdx.x;
    if (i >= n4) return;
    float4 v = ((const float4*)x)[i];
    f16x4 h, l;
    h[0]=(_Float16)v.x; l[0]=(_Float16)(v.x-(float)h[0]);
    h[1]=(_Float16)v.y; l[1]=(_Float16)(v.y-(float)h[1]);
    h[2]=(_Float16)v.z; l[2]=(_Float16)(v.z-(float)h[2]);
    h[3]=(_Float16)v.w; l[3]=(_Float16)(v.w-(float)h[3]);
    ((f16x4*)xh)[i] = h;
    ((f16x4*)xl)[i] = l;
}

__global__ __launch_bounds__(256) void cvt_w_t(
    const float* __restrict__ in, _Float16* __restrict__ outh,
    _Float16* __restrict__ outl, int K, int N, int Kp)
{
    __shared__ float tile[32][33];
    const int t = threadIdx.x;
    const int tk0 = blockIdx.x * 32, tn0 = blockIdx.y * 32;
    const int lx = t & 31, ly = t >> 5;
    #pragma unroll
    for (int r = 0; r < 4; ++r) {
        int k = tk0 + ly + r * 8, n = tn0 + lx;
        tile[ly + r * 8][lx] = (k < K && n < N) ? in[(size_t)k * N + n] : 0.f;
    }
    __syncthreads();
    #pragma unroll
    for (int r = 0; r < 4; ++r) {
        int n = tn0 + ly + r * 8, k = tk0 + lx;
        float v = tile[lx][ly + r * 8];
        _Float16 h = (_Float16)v;
        outh[(size_t)n * Kp + k] = h;
        if (outl) outl[(size_t)n * Kp + k] = (_Float16)(v - (float)h);
    }
}

// ============ split-K reduce ============
__global__ __launch_bounds__(256) void reduce_bias(
    const float* __restrict__ part, int S, int MN, int N,
    const float* __restrict__ bias, float* __restrict__ C, int act)
{
    int i = blockIdx.x * 256 + threadIdx.x;
    if (i >= MN) return;
    float s = bias[i % N];
    for (int k = 0; k < S; ++k) s += part[(size_t)k * MN + i];
    if (act == ACT_SIGMOID) s = 1.f / (1.f + __builtin_amdgcn_exp2f(-s * 1.44269504f));
    C[i] = s;
}

// ============ BatchNorm ============
__global__ __launch_bounds__(256) void colstats_partial(
    const float* __restrict__ Y, float* __restrict__ part,
    int Brows, int N, int rowsPerBlock)
{
    const int t = threadIdx.x;
    const int col = blockIdx.x * 64 + (t & 63);
    const int g = blockIdx.y;
    const int r0 = g * rowsPerBlock;
    const int r1 = min(r0 + rowsPerBlock, Brows);
    float s = 0.f, s2 = 0.f;
    for (int r = r0 + (t >> 6); r < r1; r += 4) {
        float v = Y[(size_t)r * N + col];
        s += v;
        s2 += v * v;
    }
    __shared__ float ss[4][64], ss2[4][64];
    ss[t >> 6][t & 63] = s;
    ss2[t >> 6][t & 63] = s2;
    __syncthreads();
    if (t < 64) {
        s  = ss[0][t] + ss[1][t] + ss[2][t] + ss[3][t];
        s2 = ss2[0][t] + ss2[1][t] + ss2[2][t] + ss2[3][t];
        float* p = part + ((size_t)g * N + col) * 2;
        p[0] = s;
        p[1] = s2;
    }
}

__global__ __launch_bounds__(256) void colstats_final(
    const float* __restrict__ part, int G, int N, int Brows,
    const float* __restrict__ gamma, const float* __restrict__ beta,
    float* __restrict__ scale, float* __restrict__ shift)
{
    int c = blockIdx.x * 256 + threadIdx.x;
    if (c >= N) return;
    float s = 0.f, s2 = 0.f;
    for (int g = 0; g < G; ++g) {
        s  += part[((size_t)g * N + c) * 2];
        s2 += part[((size_t)g * N + c) * 2 + 1];
    }
    float invB = 1.f / (float)Brows;
    float mean = s * invB;
    float var  = s2 * invB - mean * mean;
    float rstd = rsqrtf(var + 1e-5f);
    float sc = gamma[c] * rstd;
    scale[c] = sc;
    shift[c] = beta[c] - mean * sc;
}

__global__ __launch_bounds__(256) void bn_apply_f16(
    const float* __restrict__ Y, const float* __restrict__ scale,
    const float* __restrict__ shift, _Float16* __restrict__ oh,
    _Float16* __restrict__ ol, int total, int N, int act)
{
    int idx = blockIdx.x * 256 + threadIdx.x;
    int i4 = idx * 4;
    if (i4 >= total) return;
    float4 y = *(const float4*)(Y + i4);
    int c = i4 % N;
    float4 sc = *(const float4*)(scale + c);
    float4 sh = *(const float4*)(shift + c);
    float r[4];
    r[0] = y.x * sc.x + sh.x;
    r[1] = y.y * sc.y + sh.y;
    r[2] = y.z * sc.z + sh.z;
    r[3] = y.w * sc.w + sh.w;
    #pragma unroll
    for (int q = 0; q < 4; ++q) {
        if (act == ACT_RELU) r[q] = fmaxf(r[q], 0.f);
        else if (act == ACT_LEAKY) r[q] = (r[q] >= 0.f) ? r[q] : 0.01f * r[q];
    }
    f16x4 h;
    #pragma unroll
    for (int q = 0; q < 4; ++q) h[q] = (_Float16)r[q];
    ((f16x4*)oh)[idx] = h;
    if (ol) {
        f16x4 l;
        #pragma unroll
        for (int q = 0; q < 4; ++q) l[q] = (_Float16)(r[q] - (float)h[q]);
        ((f16x4*)ol)[idx] = l;
    }
}

// ============ Gumbel subset scan v3: linear W-space, stale-max, 1 barrier ====
// Softmax is scale-invariant: oh = (W*rm)^10 / sum((W*rm)^10) for ANY rm>0.
// W is non-increasing (mask <= 1), so last iteration's max is a valid upper
// bound -> r = W*rm <= 1, no overflow; underflowing elements are <= 2^-126 of
// max (negligible). One combined (max,sum) reduce + one barrier per iter;
// v_rcp instead of full divides; 4-mul r^10; float2-packed arithmetic.
// Thread t owns elements [8t, 8t+8) of its row (float4 loads, f16x8 store).
__global__ __launch_bounds__(256) void gumbel_scan(
    const float* __restrict__ WLg, const float* __restrict__ U,
    const float* __restrict__ X, _Float16* __restrict__ XM)
{
    const int row = blockIdx.x;
    const int t = threadIdx.x, wv = t >> 6, lane = t & 63;
    const float* wrow = WLg + (size_t)row * D_DIM + 8 * t;
    const float* urow = U + (size_t)row * D_DIM + 8 * t;
    const float* xrow = X + (size_t)row * D_DIM + 8 * t;
    _Float16* xmrow = XM + (size_t)row * D_DIM + 8 * t;

    const float L2E = 1.4426950408889634f;
    const float LOG2LN2 = -0.5287663729448977f;

    __shared__ f32x2 sLS[2][4];   // {max, sum} per wave, alternating slots
    __shared__ float sM0[4];

    f32x2 W2[4], e2[4], acc2[4];

    auto mkW = [&](float wl, float uu) -> float {
        float u = fmaf(uu, 1.0f - 1e-10f, 1e-10f);
        float tl = -__builtin_amdgcn_logf(u);            // -log2(u) > 0
        return __builtin_amdgcn_exp2f(fmaf(wl, L2E, __builtin_amdgcn_logf(tl) + LOG2LN2));
    };

    {
        float4 ua = *(const float4*)urow, ub = *(const float4*)(urow + 4);
        float4 wa = *(const float4*)wrow, wb = *(const float4*)(wrow + 4);
        W2[0] = f32x2{mkW(wa.x, ua.x), mkW(wa.y, ua.y)};
        W2[1] = f32x2{mkW(wa.z, ua.z), mkW(wa.w, ua.w)};
        W2[2] = f32x2{mkW(wb.x, ub.x), mkW(wb.y, ub.y)};
        W2[3] = f32x2{mkW(wb.z, ub.z), mkW(wb.w, ub.w)};
    }
    #pragma unroll
    for (int j = 0; j < 4; ++j) {
        e2[j] = f32x2{0.f, 0.f};
        acc2[j] = f32x2{0.f, 0.f};
    }

    // initial exact max
    float m;
    {
        f32x2 lv = f32x2{0.f, 0.f};
        #pragma unroll
        for (int j = 0; j < 4; ++j) {
            lv.x = fmaxf(lv.x, W2[j].x);
            lv.y = fmaxf(lv.y, W2[j].y);
        }
        float lm = fmaxf(lv.x, lv.y);
        #pragma unroll
        for (int off = 32; off; off >>= 1)
            lm = fmaxf(lm, __shfl_xor(lm, off));
        if (lane == 0) sM0[wv] = lm;
        __syncthreads();
        m = fmaxf(fmaxf(sM0[0], sM0[1]), fmaxf(sM0[2], sM0[3]));
    }

    float inv = 0.f;
    for (int it = 0; it < 64; ++it) {
        const int p = it & 1;
        const float rm = __builtin_amdgcn_rcpf(m);
        f32x2 lmv = f32x2{0.f, 0.f}, sv = f32x2{0.f, 0.f};
        #pragma unroll
        for (int j = 0; j < 4; ++j) {
            f32x2 oh = e2[j] * inv;
            acc2[j] += oh;
            f32x2 msk = 1.0f - oh;
            msk.x = fmaxf(msk.x, 1e-10f);
            msk.y = fmaxf(msk.y, 1e-10f);
            f32x2 Wn = W2[j] * msk;
            W2[j] = Wn;
            f32x2 r = Wn * rm;            // <= 1 (+~1ulp from rcp)
            f32x2 q2 = r * r;
            f32x2 q4 = q2 * q2;
            f32x2 q8 = q4 * q4;
            f32x2 ee = q8 * q2;           // r^10
            e2[j] = ee;
            sv += ee;
            lmv.x = fmaxf(lmv.x, Wn.x);
            lmv.y = fmaxf(lmv.y, Wn.y);
        }
        float lm = fmaxf(lmv.x, lmv.y);
        float s = sv.x + sv.y;
        #pragma unroll
        for (int off = 32; off; off >>= 1) {
            lm = fmaxf(lm, __shfl_xor(lm, off));
            s += __shfl_xor(s, off);
        }
        if (lane == 0) sLS[p][wv] = f32x2{lm, s};
        __syncthreads();
        f32x2 r0 = sLS[p][0], r1 = sLS[p][1], r2 = sLS[p][2], r3 = sLS[p][3];
        m = fmaxf(fmaxf(r0.x, r1.x), fmaxf(r2.x, r3.x));
        float st = (r0.y + r1.y) + (r2.y + r3.y);
        inv = __builtin_amdgcn_rcpf(st);
    }

    // final flush + write xm = x * khot
    {
        float4 xa = *(const float4*)xrow, xb = *(const float4*)(xrow + 4);
        f32x2 a0 = acc2[0] + e2[0] * inv;
        f32x2 a1 = acc2[1] + e2[1] * inv;
        f32x2 a2 = acc2[2] + e2[2] * inv;
        f32x2 a3 = acc2[3] + e2[3] * inv;
        f16x8 o;
        o[0] = (_Float16)(xa.x * a0.x);
        o[1] = (_Float16)(xa.y * a0.y);
        o[2] = (_Float16)(xa.z * a1.x);
        o[3] = (_Float16)(xa.w * a1.y);
        o[4] = (_Float16)(xb.x * a2.x);
        o[5] = (_Float16)(xb.y * a2.y);
        o[6] = (_Float16)(xb.z * a3.x);
        o[7] = (_Float16)(xb.w * a3.y);
        *(f16x8*)xmrow = o;
    }
}

// ============ z = mu + eps * exp(0.5*logvar) -> f16, padded to 512 cols ======
__global__ __launch_bounds__(256) void z_kernel16(
    const float* __restrict__ mu, const float* __restrict__ lv,
    const float* __restrict__ eps, _Float16* __restrict__ zb, int n4)
{
    int i = blockIdx.x * 256 + threadIdx.x;
    if (i >= n4) return;
    int f = i * 4;
    int row = f / Z_DIM, col = f - row * Z_DIM;
    float4 m = *(const float4*)(mu + f);
    float4 l = *(const float4*)(lv + f);
    float4 e = *(const float4*)(eps + f);
    const float HL2E = 0.7213475204444817f;
    f16x4 r;
    r[0] = (_Float16)(m.x + e.x * __builtin_amdgcn_exp2f(l.x * HL2E));
    r[1] = (_Float16)(m.y + e.y * __builtin_amdgcn_exp2f(l.y * HL2E));
    r[2] = (_Float16)(m.z + e.z * __builtin_amdgcn_exp2f(l.z * HL2E));
    r[3] = (_Float16)(m.w + e.w * __builtin_amdgcn_exp2f(l.w * HL2E));
    *(f16x4*)(zb + (size_t)row * 512 + col) = r;
}

extern "C" void kernel_launch(void* const* d_in, const int* in_sizes, int n_in,
                              void* d_out, int out_size, void* d_ws, size_t ws_size,
                              hipStream_t stream) {
    const float* x        = (const float*)d_in[0];
    const float* u_gumbel = (const float*)d_in[1];
    const float* eps      = (const float*)d_in[2];
    const float* wc_w1    = (const float*)d_in[3];
    const float* wc_b1    = (const float*)d_in[4];
    const float* wc_g     = (const float*)d_in[5];
    const float* wc_beta  = (const float*)d_in[6];
    const float* wc_w2    = (const float*)d_in[7];
    const float* wc_b2    = (const float*)d_in[8];
    const float* enc_w1   = (const float*)d_in[9];
    const float* enc_b1   = (const float*)d_in[10];
    const float* enc_g1   = (const float*)d_in[11];
    const float* enc_beta1= (const float*)d_in[12];
    const float* enc_w2   = (const float*)d_in[13];
    const float* enc_b2   = (const float*)d_in[14];
    const float* enc_g2   = (const float*)d_in[15];
    const float* enc_beta2= (const float*)d_in[16];
    const float* enc_w3   = (const float*)d_in[17];
    const float* enc_b3   = (const float*)d_in[18];
    const float* enc_g3   = (const float*)d_in[19];
    const float* enc_beta3= (const float*)d_in[20];
    const float* fc21_w   = (const float*)d_in[21];
    const float* fc21_b   = (const float*)d_in[22];
    const float* fc22_w   = (const float*)d_in[23];
    const float* fc22_b   = (const float*)d_in[24];
    const float* fc3_w    = (const float*)d_in[25];
    const float* fc3_b    = (const float*)d_in[26];
    const float* fc3_g    = (const float*)d_in[27];
    const float* fc3_beta = (const float*)d_in[28];
    const float* fc4_w    = (const float*)d_in[29];
    const float* fc4_b    = (const float*)d_in[30];

    float* out   = (float*)d_out;
    float* mu_x  = out;
    float* mu    = out + (size_t)B_DIM * D_DIM;
    float* lv    = mu + (size_t)B_DIM * Z_DIM;

    const size_t F1M = 1u << 20;
    float* wsf = (float*)d_ws;
    float*     P_WL  = wsf;
    _Float16*  xh    = (_Float16*)(wsf + 4 * F1M);
    _Float16*  xl    = (_Float16*)(wsf + 6 * F1M);
    _Float16*  xm16  = (_Float16*)(wsf + 4 * F1M);
    float*     Yb    = wsf + 6 * F1M;
    _Float16*  a2    = (_Float16*)(wsf + 8 * F1M);
    _Float16*  a3    = (_Float16*)(wsf + 9 * F1M);
    _Float16*  a4    = (_Float16*)(wsf + 9 * F1M + F1M / 2);
    _Float16*  zb16  = (_Float16*)(wsf + 10 * F1M);
    _Float16*  a5    = (_Float16*)(wsf + 10 * F1M + F1M / 2);
    float*     Hbuf  = wsf + 11 * F1M;
    _Float16*  Hh    = (_Float16*)(wsf + 12 * F1M);
    _Float16*  Hl    = (_Float16*)(wsf + 12 * F1M + F1M / 2);
    _Float16*  w1th  = (_Float16*)(wsf + 13 * F1M);
    _Float16*  w1tl  = (_Float16*)(wsf + 13 * F1M + F1M / 2);
    _Float16*  w2th  = (_Float16*)(wsf + 14 * F1M);
    _Float16*  w2tl  = (_Float16*)(wsf + 14 * F1M + F1M / 2);
    _Float16*  e1t   = (_Float16*)(wsf + 15 * F1M);
    _Float16*  e2t   = (_Float16*)(wsf + 16 * F1M);
    _Float16*  e3t   = (_Float16*)(wsf + 16 * F1M + F1M / 4);
    _Float16*  f21t  = (_Float16*)(wsf + 16 * F1M + 3 * (F1M / 8));
    _Float16*  f22t  = (_Float16*)(wsf + 16 * F1M + 4 * (F1M / 8));
    _Float16*  f3t   = (_Float16*)(wsf + 16 * F1M + 5 * (F1M / 8));
    _Float16*  f4t   = (_Float16*)(wsf + 16 * F1M + 6 * (F1M / 8));
    float*     bnp   = wsf + 17 * F1M + F1M / 4;
    float*     scale = bnp + 16384;
    float*     shift = scale + 2048;

    const int G = 8;

    auto gemm3 = [&](const _Float16* Ah, const _Float16* Al,
                     const _Float16* Bh, const _Float16* Bl,
                     const float* b, float* C, float* part,
                     int N, int K, int SK) {
        dim3 grid((N + 63) / 64, B_DIM / 128, SK);
        gemm_f16<128, 64, 3><<<grid, 256, 0, stream>>>(Ah, Al, Bh, Bl, b, C, part,
                                                       B_DIM, N, K, ACT_NONE, K / SK);
    };
    auto gemm1 = [&](const _Float16* Ah, const _Float16* Bh,
                     const float* b, float* C, float* part,
                     int N, int K, int act, int SK) {
        dim3 grid((N + 63) / 64, B_DIM / 128, SK);
        gemm_f16<128, 64, 1><<<grid, 256, 0, stream>>>(Ah, nullptr, Bh, nullptr, b, C,
                                                       part, B_DIM, N, K, act, K / SK);
    };
    auto reduceK = [&](const float* part, int S, int N, const float* b, float* C) {
        int MN = B_DIM * N;
        reduce_bias<<<(MN + 255) / 256, 256, 0, stream>>>(part, S, MN, N, b, C, ACT_NONE);
    };
    auto bn = [&](const float* Y, const float* g_, const float* b_,
                  _Float16* oh, _Float16* ol, int N, int act) {
        dim3 gp(N / 64, G);
        colstats_partial<<<gp, 256, 0, stream>>>(Y, bnp, B_DIM, N, B_DIM / G);
        colstats_final<<<(N + 255) / 256, 256, 0, stream>>>(bnp, G, N, B_DIM, g_, b_, scale, shift);
        int total = B_DIM * N;
        bn_apply_f16<<<(total / 4 + 255) / 256, 256, 0, stream>>>(Y, scale, shift, oh, ol, total, N, act);
    };
    auto cvtw = [&](const float* in, _Float16* oh, _Float16* ol, int K, int N, int Kp, int Np) {
        dim3 grid(Kp / 32, Np / 32);
        cvt_w_t<<<grid, 256, 0, stream>>>(in, oh, ol, K, N, Kp);
    };

    // ---- converts ----
    cvt_split_x<<<4096, 256, 0, stream>>>(x, xh, xl, B_DIM * D_DIM / 4);
    cvtw(wc_w1, w1th, w1tl, 2048, 512, 2048, 512);
    cvtw(wc_w2, w2th, w2tl, 512, 2048, 512, 2048);
    cvtw(enc_w1, e1t, nullptr, 2048, 1024, 2048, 1024);
    cvtw(enc_w2, e2t, nullptr, 1024, 512, 1024, 512);
    cvtw(enc_w3, e3t, nullptr, 512, 512, 512, 512);
    cvtw(fc21_w, f21t, nullptr, 512, 500, 512, 512);
    cvtw(fc22_w, f22t, nullptr, 512, 500, 512, 512);
    cvtw(fc3_w, f3t, nullptr, 500, 512, 512, 512);
    cvtw(fc4_w, f4t, nullptr, 512, 2048, 512, 2048);

    // ---- weight_creator ----
    gemm3(xh, xl, w1th, w1tl, nullptr, nullptr, P_WL, 512, 2048, 4);
    reduceK(P_WL, 4, 512, wc_b1, Hbuf);
    bn(Hbuf, wc_g, wc_beta, Hh, Hl, 512, ACT_RELU);
    gemm3(Hh, Hl, w2th, w2tl, wc_b2, P_WL, nullptr, 2048, 512, 1);  // -> WL

    // ---- gumbel scan: WL -> xm16 (f16) ----
    gumbel_scan<<<B_DIM, 256, 0, stream>>>(P_WL, u_gumbel, x, xm16);

    // ---- encoder ----
    gemm1(xm16, e1t, nullptr, nullptr, P_WL, 1024, 2048, ACT_NONE, 2);
    reduceK(P_WL, 2, 1024, enc_b1, Yb);
    bn(Yb, enc_g1, enc_beta1, a2, nullptr, 1024, ACT_LEAKY);
    gemm1(a2, e2t, nullptr, nullptr, P_WL, 512, 1024, ACT_NONE, 4);
    reduceK(P_WL, 4, 512, enc_b2, Yb);
    bn(Yb, enc_g2, enc_beta2, a3, nullptr, 512, ACT_LEAKY);
    gemm1(a3, e3t, nullptr, nullptr, P_WL, 512, 512, ACT_NONE, 4);
    reduceK(P_WL, 4, 512, enc_b3, Yb);
    bn(Yb, enc_g3, enc_beta3, a4, nullptr, 512, ACT_LEAKY);

    // ---- heads ----
    gemm1(a4, f21t, nullptr, nullptr, P_WL, 500, 512, ACT_NONE, 4);
    reduceK(P_WL, 4, 500, fc21_b, mu);
    gemm1(a4, f22t, nullptr, nullptr, P_WL, 500, 512, ACT_NONE, 4);
    reduceK(P_WL, 4, 500, fc22_b, lv);

    // ---- reparameterize ----
    hipMemsetAsync(zb16, 0, (size_t)B_DIM * 512 * sizeof(_Float16), stream);
    int n4 = B_DIM * Z_DIM / 4;
    z_kernel16<<<(n4 + 255) / 256, 256, 0, stream>>>(mu, lv, eps, zb16, n4);

    // ---- decoder ----
    gemm1(zb16, f3t, nullptr, nullptr, P_WL, 512, 512, ACT_NONE, 4);
    reduceK(P_WL, 4, 512, fc3_b, Yb);
    bn(Yb, fc3_g, fc3_beta, a5, nullptr, 512, ACT_LEAKY);
    gemm1(a5, f4t, fc4_b, mu_x, nullptr, 2048, 512, ACT_SIGMOID, 1);
}